// Round 4
// baseline (467.701 us; speedup 1.0000x reference)
//
#include <hip/hip_runtime.h>

#define S_LEN 4096
#define DMODEL 1024
#define NH 16
#define NKV 4
#define HDIM 64
#define NQKV 1536  /* (16+2*4)*64 */

typedef __attribute__((ext_vector_type(8))) short bfrag8;
typedef __attribute__((ext_vector_type(4))) float f32x4_t;

__device__ __forceinline__ unsigned short f2bf(float f) {
  unsigned int u = __builtin_bit_cast(unsigned int, f);
  return (unsigned short)((u + 0x7fffu + ((u >> 16) & 1u)) >> 16);
}

// ---------------- elementwise f32 -> bf16 ----------------
__global__ void convert_bf16(const float* __restrict__ in, unsigned short* __restrict__ out, int n) {
  int idx = (blockIdx.x * 256 + threadIdx.x) * 4;
  if (idx < n) {
    float4 v = *reinterpret_cast<const float4*>(in + idx);
    out[idx + 0] = f2bf(v.x);
    out[idx + 1] = f2bf(v.y);
    out[idx + 2] = f2bf(v.z);
    out[idx + 3] = f2bf(v.w);
  }
}

// ---------------- tiled transpose + convert: out[c][r] = bf16(in[r][c]) ----------------
__global__ void transpose_convert(const float* __restrict__ in, int ldin, long in_zstride,
                                  unsigned short* __restrict__ out, int ldout, long out_zstride,
                                  int R, int C) {
  __shared__ float tile[32][33];
  const float* inb = in + (size_t)blockIdx.z * in_zstride;
  unsigned short* outb = out + (size_t)blockIdx.z * out_zstride;
  int c0 = blockIdx.x * 32, r0 = blockIdx.y * 32;
  int tx = threadIdx.x, ty = threadIdx.y;  // 32 x 8
  for (int i = 0; i < 4; ++i) {
    int r = r0 + ty + i * 8;
    tile[ty + i * 8][tx] = inb[(size_t)r * ldin + c0 + tx];
  }
  __syncthreads();
  for (int i = 0; i < 4; ++i) {
    int c = c0 + ty + i * 8;
    outb[(size_t)c * ldout + r0 + tx] = f2bf(tile[tx][ty + i * 8]);
  }
}

// ---------------- RoPE; Q pre-scaled by 0.125*log2(e) so QK^T lands in exp2 domain ----------------
__global__ void rope_kernel(const float* __restrict__ qkv,
                            const float* __restrict__ pcos, const float* __restrict__ psin,
                            unsigned short* __restrict__ Qh, unsigned short* __restrict__ Kh) {
  const float SCL = 0.125f * 1.44269504f;
  int s = blockIdx.x;
  int t = threadIdx.x;
  const float* row = qkv + (size_t)s * NQKV;
  for (int p = t; p < 640; p += 256) {
    int i = p & 31;
    float c = pcos[s * 32 + i], sn = psin[s * 32 + i];
    if (p < 512) {
      int h = p >> 5;
      float te = row[h * 64 + 2 * i], to = row[h * 64 + 2 * i + 1];
      size_t base = ((size_t)h * S_LEN + s) * 64;
      Qh[base + 2 * i]     = f2bf((te * c - to * sn) * SCL);
      Qh[base + 2 * i + 1] = f2bf((te * sn + to * c) * SCL);
    } else {
      int hk = (p - 512) >> 5;
      float te = row[1024 + hk * 64 + 2 * i], to = row[1024 + hk * 64 + 2 * i + 1];
      size_t base = ((size_t)hk * S_LEN + s) * 64;
      Kh[base + 2 * i]     = f2bf(te * c - to * sn);
      Kh[base + 2 * i + 1] = f2bf(te * sn + to * c);
    }
  }
}

// ---------------- bf16 MFMA GEMM: C(MxN,f32) = A(MxK) * Bt(NxK)^T ----------------
#define BM 128
#define BN 128
#define BK 32
#define LDSW 40

__global__ __launch_bounds__(256) void gemm_bf16(
    const unsigned short* __restrict__ A,
    const unsigned short* __restrict__ Bt,
    float* __restrict__ C, int M, int N, int K) {
  __shared__ unsigned short As[BM * LDSW];
  __shared__ unsigned short Bs[BN * LDSW];
  int m0 = blockIdx.x * BM, n0 = blockIdx.y * BN;
  int t = threadIdx.x, lane = t & 63, wid = t >> 6;
  int wm = (wid >> 1) * 64, wn = (wid & 1) * 64;
  int fr = lane & 15, kb = lane >> 4;
  f32x4_t acc[4][4];
  for (int r = 0; r < 4; ++r)
    for (int c = 0; c < 4; ++c) acc[r][c] = (f32x4_t){0.f, 0.f, 0.f, 0.f};

  for (int k0 = 0; k0 < K; k0 += BK) {
    __syncthreads();
    for (int i = 0; i < 2; ++i) {
      int idx = (i * 256 + t) * 8;
      int r = idx >> 5, c = idx & 31;
      bfrag8 va = *reinterpret_cast<const bfrag8*>(A + (size_t)(m0 + r) * K + k0 + c);
      *reinterpret_cast<bfrag8*>(&As[r * LDSW + c]) = va;
      bfrag8 vb = *reinterpret_cast<const bfrag8*>(Bt + (size_t)(n0 + r) * K + k0 + c);
      *reinterpret_cast<bfrag8*>(&Bs[r * LDSW + c]) = vb;
    }
    __syncthreads();
    bfrag8 af[4], bfr[4];
    for (int rb = 0; rb < 4; ++rb)
      af[rb] = *reinterpret_cast<const bfrag8*>(&As[(wm + rb * 16 + fr) * LDSW + kb * 8]);
    for (int cb = 0; cb < 4; ++cb)
      bfr[cb] = *reinterpret_cast<const bfrag8*>(&Bs[(wn + cb * 16 + fr) * LDSW + kb * 8]);
    for (int rb = 0; rb < 4; ++rb)
      for (int cb = 0; cb < 4; ++cb)
        acc[rb][cb] = __builtin_amdgcn_mfma_f32_16x16x32_bf16(af[rb], bfr[cb], acc[rb][cb], 0, 0, 0);
  }
  int rowg = (lane >> 4) * 4, colg = lane & 15;
  for (int rb = 0; rb < 4; ++rb)
    for (int cb = 0; cb < 4; ++cb)
      for (int j = 0; j < 4; ++j) {
        int r = m0 + wm + rb * 16 + rowg + j;
        int c = n0 + wn + cb * 16 + colg;
        C[(size_t)r * N + c] = acc[rb][cb][j];
      }
}

// ---------------- flash attention: causal, GQA, swapped-QK^T, 4-way KV split, K-prefetch ----------------
// Qh [NH][S][64] (pre-scaled), Kh [NKV][S][64], Vt [NKV][64][S], aout [S][NH*64] bf16
// Block: 256 thr = 4 waves; all 4 waves share one (head, 16-row q-tile), each takes 1/4 of KV range.
#define PLDS 72

__global__ __launch_bounds__(256, 4) void flash_attn(
    const unsigned short* __restrict__ Qh,
    const unsigned short* __restrict__ Kh,
    const unsigned short* __restrict__ Vt,
    unsigned short* __restrict__ aout) {
  __shared__ unsigned short Pl[4][16 * PLDS];
  __shared__ float ACCs[3][64][16];  // [wave-1][dt*16+row][fr]
  __shared__ float MLs[4][2][16];    // [wave][{m,l}][row]

  int h = blockIdx.y, hk = h >> 2;
  int qt = gridDim.x - 1 - blockIdx.x;  // longest chains dispatch first
  int qrow0 = qt * 16;
  int t = threadIdx.x, lane = t & 63, wid = t >> 6;
  int fr = lane & 15, kb = lane >> 4, rloc = kb * 4;
  unsigned short* Pw = &Pl[wid][0];

  // Q B-frags
  const unsigned short* Qbase = Qh + ((size_t)h * S_LEN + qrow0) * 64;
  bfrag8 qf0 = *reinterpret_cast<const bfrag8*>(Qbase + fr * 64 + kb * 8);
  bfrag8 qf1 = *reinterpret_cast<const bfrag8*>(Qbase + fr * 64 + 32 + kb * 8);

  const unsigned short* Kbh = Kh + (size_t)hk * S_LEN * 64;
  const unsigned short* Vbh = Vt + (size_t)hk * 64 * S_LEN;

  float m_r = -1e30f, l_r = 0.f;
  f32x4_t acc[4];
#pragma unroll
  for (int dt = 0; dt < 4; ++dt) acc[dt] = (f32x4_t){0.f, 0.f, 0.f, 0.f};

  int ntt = (qrow0 + 79) / 64;                          // total KV tiles for this q-tile
  int nf = (qrow0 >= 63) ? ((qrow0 - 63) / 64 + 1) : 0; // fully-unmasked tiles
  int c0 = (wid * ntt) >> 2, c1 = ((wid + 1) * ntt) >> 2;

  bfrag8 kf[4][2], vf[2][4];
  auto LOAD_K = [&](int kt) {
    int kv0 = kt * 64;
#pragma unroll
    for (int ct = 0; ct < 4; ++ct) {
      const unsigned short* Kb = Kbh + (size_t)(kv0 + ct * 16 + fr) * 64 + kb * 8;
      kf[ct][0] = *reinterpret_cast<const bfrag8*>(Kb);
      kf[ct][1] = *reinterpret_cast<const bfrag8*>(Kb + 32);
    }
  };
  auto LOAD_V = [&](int kt) {
    int kv0 = kt * 64;
#pragma unroll
    for (int hh = 0; hh < 2; ++hh)
#pragma unroll
      for (int dt = 0; dt < 4; ++dt)
        vf[hh][dt] = *reinterpret_cast<const bfrag8*>(
            Vbh + (size_t)(dt * 16 + fr) * S_LEN + kv0 + hh * 32 + kb * 8);
  };

  if (c0 < c1) {
    LOAD_K(c0);
    LOAD_V(c0);
    for (int kt = c0; kt < c1; ++kt) {
      int kv0 = kt * 64;
      // swapped QK^T: lane (kb,fr) holds q-row fr, k-cols ct*16+kb*4+j
      f32x4_t sc[4];
      __builtin_amdgcn_s_setprio(1);
#pragma unroll
      for (int ct = 0; ct < 4; ++ct) {
        f32x4_t z = (f32x4_t){0.f, 0.f, 0.f, 0.f};
        z = __builtin_amdgcn_mfma_f32_16x16x32_bf16(kf[ct][0], qf0, z, 0, 0, 0);
        sc[ct] = __builtin_amdgcn_mfma_f32_16x16x32_bf16(kf[ct][1], qf1, z, 0, 0, 0);
      }
      __builtin_amdgcn_s_setprio(0);
      // prefetch next tile's K while softmax+PV run (wait lands before next QK)
      if (kt + 1 < c1) LOAD_K(kt + 1);
      if (kt >= nf) {
        int grow = qrow0 + fr;
#pragma unroll
        for (int ct = 0; ct < 4; ++ct)
#pragma unroll
          for (int j = 0; j < 4; ++j)
            sc[ct][j] = ((kv0 + ct * 16 + kb * 4 + j) <= grow) ? sc[ct][j] : -1e30f;
      }
      // row max: lane-local tree + 2 shuffles
      float pm0 = fmaxf(fmaxf(sc[0][0], sc[0][1]), fmaxf(sc[0][2], sc[0][3]));
      float pm1 = fmaxf(fmaxf(sc[1][0], sc[1][1]), fmaxf(sc[1][2], sc[1][3]));
      float pm2 = fmaxf(fmaxf(sc[2][0], sc[2][1]), fmaxf(sc[2][2], sc[2][3]));
      float pm3 = fmaxf(fmaxf(sc[3][0], sc[3][1]), fmaxf(sc[3][2], sc[3][3]));
      float pmax = fmaxf(fmaxf(pm0, pm1), fmaxf(pm2, pm3));
      pmax = fmaxf(pmax, __shfl_xor(pmax, 16));
      pmax = fmaxf(pmax, __shfl_xor(pmax, 32));
      // defer-max: rescale only when max rose by > 8 (exp2 domain)
      if (__any(pmax > m_r + 8.0f)) {
        float mnew = fmaxf(m_r, pmax);
        float a = exp2f(m_r - mnew);
        l_r *= a;
        m_r = mnew;
#pragma unroll
        for (int j = 0; j < 4; ++j) {
          float aj = __shfl(a, rloc + j);
#pragma unroll
          for (int dt = 0; dt < 4; ++dt) acc[dt][j] *= aj;
        }
      }
      // P = exp2(s - m), lane-local sum + 2 shuffles
      float s = 0.f;
#pragma unroll
      for (int ct = 0; ct < 4; ++ct) {
#pragma unroll
        for (int j = 0; j < 4; ++j) {
          float p = exp2f(sc[ct][j] - m_r);
          sc[ct][j] = p;
          s += p;
        }
      }
      s += __shfl_xor(s, 16);
      s += __shfl_xor(s, 32);
      l_r += s;
      // P -> per-wave LDS (row q=fr, cols ct*16+kb*4+{0..3}); packed b64 writes
#pragma unroll
      for (int ct = 0; ct < 4; ++ct) {
        unsigned int u01 = (unsigned int)f2bf(sc[ct][0]) | ((unsigned int)f2bf(sc[ct][1]) << 16);
        unsigned int u23 = (unsigned int)f2bf(sc[ct][2]) | ((unsigned int)f2bf(sc[ct][3]) << 16);
        unsigned long long w = ((unsigned long long)u23 << 32) | u01;
        *reinterpret_cast<unsigned long long*>(&Pw[fr * PLDS + ct * 16 + kb * 4]) = w;
      }
      // PV: A = P (rows=q), B = V
      __builtin_amdgcn_s_setprio(1);
#pragma unroll
      for (int hh = 0; hh < 2; ++hh) {
        bfrag8 pa = *reinterpret_cast<const bfrag8*>(Pw + fr * PLDS + hh * 32 + kb * 8);
#pragma unroll
        for (int dt = 0; dt < 4; ++dt)
          acc[dt] = __builtin_amdgcn_mfma_f32_16x16x32_bf16(pa, vf[hh][dt], acc[dt], 0, 0, 0);
      }
      __builtin_amdgcn_s_setprio(0);
      // prefetch next tile's V (wait lands before next PV, behind QK+softmax)
      if (kt + 1 < c1) LOAD_V(kt + 1);
    }
  }

  // ---- 4-way merge ----
  if (wid > 0) {
#pragma unroll
    for (int dt = 0; dt < 4; ++dt)
#pragma unroll
      for (int j = 0; j < 4; ++j)
        ACCs[wid - 1][dt * 16 + rloc + j][fr] = acc[dt][j];
  }
  if (lane < 16) {
    MLs[wid][0][lane] = m_r;
    MLs[wid][1][lane] = l_r;
  }
  __syncthreads();
  if (wid == 0) {
#pragma unroll
    for (int j = 0; j < 4; ++j) {
      int row = rloc + j;
      float m0 = MLs[0][0][row], m1 = MLs[1][0][row];
      float m2 = MLs[2][0][row], m3 = MLs[3][0][row];
      float mm = fmaxf(fmaxf(m0, m1), fmaxf(m2, m3));
      float cw0 = exp2f(m0 - mm), cw1 = exp2f(m1 - mm);
      float cw2 = exp2f(m2 - mm), cw3 = exp2f(m3 - mm);
      float inv = 1.0f / (MLs[0][1][row] * cw0 + MLs[1][1][row] * cw1 +
                          MLs[2][1][row] * cw2 + MLs[3][1][row] * cw3);
      int grow = qrow0 + row;
#pragma unroll
      for (int dt = 0; dt < 4; ++dt) {
        float o = acc[dt][j] * cw0 + ACCs[0][dt * 16 + row][fr] * cw1 +
                  ACCs[1][dt * 16 + row][fr] * cw2 + ACCs[2][dt * 16 + row][fr] * cw3;
        aout[(size_t)grow * (NH * HDIM) + h * 64 + dt * 16 + fr] = f2bf(o * inv);
      }
    }
  }
}

// ---------------- launch ----------------
extern "C" void kernel_launch(void* const* d_in, const int* in_sizes, int n_in,
                              void* d_out, int out_size, void* d_ws, size_t ws_size,
                              hipStream_t stream) {
  const float* x    = (const float*)d_in[0];
  const float* pcos = (const float*)d_in[1];
  const float* psin = (const float*)d_in[2];
  const float* wqkv = (const float*)d_in[3];
  const float* wo   = (const float*)d_in[4];
  float* out = (float*)d_out;

  char* ws = (char*)d_ws;
  unsigned short* xb    = (unsigned short*)ws;  ws += (size_t)S_LEN * DMODEL * 2;
  unsigned short* wqkvT = (unsigned short*)ws;  ws += (size_t)NQKV * DMODEL * 2;
  unsigned short* woT   = (unsigned short*)ws;  ws += (size_t)DMODEL * DMODEL * 2;
  float*          qkv   = (float*)ws;           ws += (size_t)S_LEN * NQKV * 4;
  unsigned short* Qh    = (unsigned short*)ws;  ws += (size_t)NH * S_LEN * HDIM * 2;
  unsigned short* Kh    = (unsigned short*)ws;  ws += (size_t)NKV * S_LEN * HDIM * 2;
  unsigned short* Vt    = (unsigned short*)ws;  ws += (size_t)NKV * HDIM * S_LEN * 2;
  unsigned short* aoutb = (unsigned short*)ws;  ws += (size_t)S_LEN * NH * HDIM * 2;

  convert_bf16<<<(S_LEN * DMODEL) / (256 * 4), 256, 0, stream>>>(x, xb, S_LEN * DMODEL);
  transpose_convert<<<dim3(NQKV / 32, DMODEL / 32, 1), dim3(32, 8), 0, stream>>>(
      wqkv, NQKV, 0, wqkvT, DMODEL, 0, DMODEL, NQKV);
  transpose_convert<<<dim3(DMODEL / 32, DMODEL / 32, 1), dim3(32, 8), 0, stream>>>(
      wo, DMODEL, 0, woT, DMODEL, 0, DMODEL, DMODEL);
  gemm_bf16<<<dim3(S_LEN / BM, NQKV / BN), 256, 0, stream>>>(xb, wqkvT, qkv, S_LEN, NQKV, DMODEL);
  rope_kernel<<<S_LEN, 256, 0, stream>>>(qkv, pcos, psin, Qh, Kh);
  transpose_convert<<<dim3(HDIM / 32, S_LEN / 32, NKV), dim3(32, 8), 0, stream>>>(
      qkv + 1280, NQKV, 64, Vt, S_LEN, (long)HDIM * S_LEN, S_LEN, HDIM);
  flash_attn<<<dim3(256, NH), 256, 0, stream>>>(Qh, Kh, Vt, aoutb);
  gemm_bf16<<<dim3(S_LEN / BM, DMODEL / BN), 256, 0, stream>>>(aoutb, woT, out, S_LEN, DMODEL, DMODEL);
}

// Round 5
// 364.299 us; speedup vs baseline: 1.2838x; 1.2838x over previous
//
#include <hip/hip_runtime.h>

#define S_LEN 4096
#define DMODEL 1024
#define NH 16
#define NKV 4
#define HDIM 64
#define NQKV 1536  /* (16+2*4)*64 */

typedef __attribute__((ext_vector_type(8))) short bfrag8;
typedef __attribute__((ext_vector_type(4))) float f32x4_t;

__device__ __forceinline__ unsigned short f2bf(float f) {
  unsigned int u = __builtin_bit_cast(unsigned int, f);
  return (unsigned short)((u + 0x7fffu + ((u >> 16) & 1u)) >> 16);
}

// ---------------- elementwise f32 -> bf16 ----------------
__global__ void convert_bf16(const float* __restrict__ in, unsigned short* __restrict__ out, int n) {
  int idx = (blockIdx.x * 256 + threadIdx.x) * 4;
  if (idx < n) {
    float4 v = *reinterpret_cast<const float4*>(in + idx);
    out[idx + 0] = f2bf(v.x);
    out[idx + 1] = f2bf(v.y);
    out[idx + 2] = f2bf(v.z);
    out[idx + 3] = f2bf(v.w);
  }
}

// ---------------- tiled transpose + convert: out[c][r] = bf16(in[r][c]) ----------------
__global__ void transpose_convert(const float* __restrict__ in, int ldin, long in_zstride,
                                  unsigned short* __restrict__ out, int ldout, long out_zstride,
                                  int R, int C) {
  __shared__ float tile[32][33];
  const float* inb = in + (size_t)blockIdx.z * in_zstride;
  unsigned short* outb = out + (size_t)blockIdx.z * out_zstride;
  int c0 = blockIdx.x * 32, r0 = blockIdx.y * 32;
  int tx = threadIdx.x, ty = threadIdx.y;  // 32 x 8
  for (int i = 0; i < 4; ++i) {
    int r = r0 + ty + i * 8;
    tile[ty + i * 8][tx] = inb[(size_t)r * ldin + c0 + tx];
  }
  __syncthreads();
  for (int i = 0; i < 4; ++i) {
    int c = c0 + ty + i * 8;
    outb[(size_t)c * ldout + r0 + tx] = f2bf(tile[tx][ty + i * 8]);
  }
}

// ---------------- RoPE; Q pre-scaled by 0.125*log2(e) so QK^T lands in exp2 domain ----------------
__global__ void rope_kernel(const float* __restrict__ qkv,
                            const float* __restrict__ pcos, const float* __restrict__ psin,
                            unsigned short* __restrict__ Qh, unsigned short* __restrict__ Kh) {
  const float SCL = 0.125f * 1.44269504f;
  int s = blockIdx.x;
  int t = threadIdx.x;
  const float* row = qkv + (size_t)s * NQKV;
  for (int p = t; p < 640; p += 256) {
    int i = p & 31;
    float c = pcos[s * 32 + i], sn = psin[s * 32 + i];
    if (p < 512) {
      int h = p >> 5;
      float te = row[h * 64 + 2 * i], to = row[h * 64 + 2 * i + 1];
      size_t base = ((size_t)h * S_LEN + s) * 64;
      Qh[base + 2 * i]     = f2bf((te * c - to * sn) * SCL);
      Qh[base + 2 * i + 1] = f2bf((te * sn + to * c) * SCL);
    } else {
      int hk = (p - 512) >> 5;
      float te = row[1024 + hk * 64 + 2 * i], to = row[1024 + hk * 64 + 2 * i + 1];
      size_t base = ((size_t)hk * S_LEN + s) * 64;
      Kh[base + 2 * i]     = f2bf(te * c - to * sn);
      Kh[base + 2 * i + 1] = f2bf(te * sn + to * c);
    }
  }
}

// ---------------- bf16 MFMA GEMM: C(MxN,f32) = A(MxK) * Bt(NxK)^T ----------------
#define BM 128
#define BN 128
#define BK 32
#define LDSW 40

__global__ __launch_bounds__(256) void gemm_bf16(
    const unsigned short* __restrict__ A,
    const unsigned short* __restrict__ Bt,
    float* __restrict__ C, int M, int N, int K) {
  __shared__ unsigned short As[BM * LDSW];
  __shared__ unsigned short Bs[BN * LDSW];
  int m0 = blockIdx.x * BM, n0 = blockIdx.y * BN;
  int t = threadIdx.x, lane = t & 63, wid = t >> 6;
  int wm = (wid >> 1) * 64, wn = (wid & 1) * 64;
  int fr = lane & 15, kb = lane >> 4;
  f32x4_t acc[4][4];
  for (int r = 0; r < 4; ++r)
    for (int c = 0; c < 4; ++c) acc[r][c] = (f32x4_t){0.f, 0.f, 0.f, 0.f};

  for (int k0 = 0; k0 < K; k0 += BK) {
    __syncthreads();
    for (int i = 0; i < 2; ++i) {
      int idx = (i * 256 + t) * 8;
      int r = idx >> 5, c = idx & 31;
      bfrag8 va = *reinterpret_cast<const bfrag8*>(A + (size_t)(m0 + r) * K + k0 + c);
      *reinterpret_cast<bfrag8*>(&As[r * LDSW + c]) = va;
      bfrag8 vb = *reinterpret_cast<const bfrag8*>(Bt + (size_t)(n0 + r) * K + k0 + c);
      *reinterpret_cast<bfrag8*>(&Bs[r * LDSW + c]) = vb;
    }
    __syncthreads();
    bfrag8 af[4], bfr[4];
    for (int rb = 0; rb < 4; ++rb)
      af[rb] = *reinterpret_cast<const bfrag8*>(&As[(wm + rb * 16 + fr) * LDSW + kb * 8]);
    for (int cb = 0; cb < 4; ++cb)
      bfr[cb] = *reinterpret_cast<const bfrag8*>(&Bs[(wn + cb * 16 + fr) * LDSW + kb * 8]);
    for (int rb = 0; rb < 4; ++rb)
      for (int cb = 0; cb < 4; ++cb)
        acc[rb][cb] = __builtin_amdgcn_mfma_f32_16x16x32_bf16(af[rb], bfr[cb], acc[rb][cb], 0, 0, 0);
  }
  int rowg = (lane >> 4) * 4, colg = lane & 15;
  for (int rb = 0; rb < 4; ++rb)
    for (int cb = 0; cb < 4; ++cb)
      for (int j = 0; j < 4; ++j) {
        int r = m0 + wm + rb * 16 + rowg + j;
        int c = n0 + wn + cb * 16 + colg;
        C[(size_t)r * N + c] = acc[rb][cb][j];
      }
}

// ---------------- flash attention: causal, GQA, swapped-QK^T, 4-way KV split, reg K-prefetch ----------------
// Qh [NH][S][64] (pre-scaled), Kh [NKV][S][64], Vt [NKV][64][S], aout [S][NH*64] bf16
// Block: 256 thr = 4 waves; all share one (head, 16-row q-tile), each takes 1/4 of the KV range.
// NOTE: kf/vf are plain arrays indexed ONLY by compile-time constants (unrolled) -> stay in VGPRs.
//       R3's lambda-captured versions were address-taken -> scratch -> 400 MB of spill traffic.
#define PLDS 72

__global__ __launch_bounds__(256) void flash_attn(
    const unsigned short* __restrict__ Qh,
    const unsigned short* __restrict__ Kh,
    const unsigned short* __restrict__ Vt,
    unsigned short* __restrict__ aout) {
  __shared__ unsigned short Pl[4][16 * PLDS];
  __shared__ float ACCs[3][64][16];  // [wave-1][dt*16+row][fr]
  __shared__ float MLs[4][2][16];    // [wave][{m,l}][row]

  int h = blockIdx.y, hk = h >> 2;
  int qt = gridDim.x - 1 - blockIdx.x;  // longest chains dispatch first
  int qrow0 = qt * 16;
  int t = threadIdx.x, lane = t & 63, wid = t >> 6;
  int fr = lane & 15, kb = lane >> 4, rloc = kb * 4;
  unsigned short* Pw = &Pl[wid][0];

  const unsigned short* Qbase = Qh + ((size_t)h * S_LEN + qrow0) * 64;
  bfrag8 qf0 = *reinterpret_cast<const bfrag8*>(Qbase + fr * 64 + kb * 8);
  bfrag8 qf1 = *reinterpret_cast<const bfrag8*>(Qbase + fr * 64 + 32 + kb * 8);

  const unsigned short* Kbh = Kh + (size_t)hk * S_LEN * 64 + (size_t)fr * 64 + kb * 8;
  const unsigned short* Vbh = Vt + (size_t)hk * 64 * S_LEN;

  float m_r = -1e30f, l_r = 0.f;
  f32x4_t acc[4];
#pragma unroll
  for (int dt = 0; dt < 4; ++dt) acc[dt] = (f32x4_t){0.f, 0.f, 0.f, 0.f};

  int ntt = (qrow0 + 79) / 64;                          // total KV tiles for this q-tile
  int nf = (qrow0 >= 63) ? ((qrow0 - 63) / 64 + 1) : 0; // fully-unmasked tiles
  int c0 = (wid * ntt) >> 2, c1 = ((wid + 1) * ntt) >> 2;

  bfrag8 kf[4][2];

  if (c0 < c1) {
    // preamble: load K for first tile
    {
      const unsigned short* Kb0 = Kbh + (size_t)c0 * 64 * 64;
#pragma unroll
      for (int ct = 0; ct < 4; ++ct) {
        kf[ct][0] = *reinterpret_cast<const bfrag8*>(Kb0 + (size_t)ct * 16 * 64);
        kf[ct][1] = *reinterpret_cast<const bfrag8*>(Kb0 + (size_t)ct * 16 * 64 + 32);
      }
    }
    for (int kt = c0; kt < c1; ++kt) {
      int kv0 = kt * 64;
      // V loads for this tile (consumed by PV at bottom; wait hides behind QK+softmax)
      bfrag8 vf[2][4];
#pragma unroll
      for (int hh = 0; hh < 2; ++hh)
#pragma unroll
        for (int dt = 0; dt < 4; ++dt)
          vf[hh][dt] = *reinterpret_cast<const bfrag8*>(
              Vbh + (size_t)(dt * 16 + fr) * S_LEN + kv0 + hh * 32 + kb * 8);
      __builtin_amdgcn_sched_barrier(0);  // pin V-load issue here (don't sink)
      // swapped QK^T: lane (kb,fr) holds q-row fr, k-cols ct*16+kb*4+j
      f32x4_t sc[4];
      __builtin_amdgcn_s_setprio(1);
#pragma unroll
      for (int ct = 0; ct < 4; ++ct) {
        f32x4_t z = (f32x4_t){0.f, 0.f, 0.f, 0.f};
        z = __builtin_amdgcn_mfma_f32_16x16x32_bf16(kf[ct][0], qf0, z, 0, 0, 0);
        sc[ct] = __builtin_amdgcn_mfma_f32_16x16x32_bf16(kf[ct][1], qf1, z, 0, 0, 0);
      }
      __builtin_amdgcn_s_setprio(0);
      // prefetch next tile's K now that QK consumed kf; softmax+PV cover the latency
      if (kt + 1 < c1) {
        const unsigned short* Kbn = Kbh + (size_t)(kt + 1) * 64 * 64;
#pragma unroll
        for (int ct = 0; ct < 4; ++ct) {
          kf[ct][0] = *reinterpret_cast<const bfrag8*>(Kbn + (size_t)ct * 16 * 64);
          kf[ct][1] = *reinterpret_cast<const bfrag8*>(Kbn + (size_t)ct * 16 * 64 + 32);
        }
      }
      __builtin_amdgcn_sched_barrier(0);  // pin K-prefetch issue above softmax
      if (kt >= nf) {
        int grow = qrow0 + fr;
#pragma unroll
        for (int ct = 0; ct < 4; ++ct)
#pragma unroll
          for (int j = 0; j < 4; ++j)
            sc[ct][j] = ((kv0 + ct * 16 + kb * 4 + j) <= grow) ? sc[ct][j] : -1e30f;
      }
      // row max: lane-local tree + 2 shuffles
      float pm0 = fmaxf(fmaxf(sc[0][0], sc[0][1]), fmaxf(sc[0][2], sc[0][3]));
      float pm1 = fmaxf(fmaxf(sc[1][0], sc[1][1]), fmaxf(sc[1][2], sc[1][3]));
      float pm2 = fmaxf(fmaxf(sc[2][0], sc[2][1]), fmaxf(sc[2][2], sc[2][3]));
      float pm3 = fmaxf(fmaxf(sc[3][0], sc[3][1]), fmaxf(sc[3][2], sc[3][3]));
      float pmax = fmaxf(fmaxf(pm0, pm1), fmaxf(pm2, pm3));
      pmax = fmaxf(pmax, __shfl_xor(pmax, 16));
      pmax = fmaxf(pmax, __shfl_xor(pmax, 32));
      // defer-max: rescale only when max rose by > 8 (exp2 domain)
      if (__any(pmax > m_r + 8.0f)) {
        float mnew = fmaxf(m_r, pmax);
        float a = exp2f(m_r - mnew);
        l_r *= a;
        m_r = mnew;
#pragma unroll
        for (int j = 0; j < 4; ++j) {
          float aj = __shfl(a, rloc + j);
#pragma unroll
          for (int dt = 0; dt < 4; ++dt) acc[dt][j] *= aj;
        }
      }
      // P = exp2(s - m), lane-local sum + 2 shuffles
      float s = 0.f;
#pragma unroll
      for (int ct = 0; ct < 4; ++ct) {
#pragma unroll
        for (int j = 0; j < 4; ++j) {
          float p = exp2f(sc[ct][j] - m_r);
          sc[ct][j] = p;
          s += p;
        }
      }
      s += __shfl_xor(s, 16);
      s += __shfl_xor(s, 32);
      l_r += s;
      // P -> per-wave LDS (row q=fr, cols ct*16+kb*4+{0..3}); packed b64 writes
#pragma unroll
      for (int ct = 0; ct < 4; ++ct) {
        unsigned int u01 = (unsigned int)f2bf(sc[ct][0]) | ((unsigned int)f2bf(sc[ct][1]) << 16);
        unsigned int u23 = (unsigned int)f2bf(sc[ct][2]) | ((unsigned int)f2bf(sc[ct][3]) << 16);
        unsigned long long w = ((unsigned long long)u23 << 32) | u01;
        *reinterpret_cast<unsigned long long*>(&Pw[fr * PLDS + ct * 16 + kb * 4]) = w;
      }
      // PV: A = P (rows=q), B = V
      __builtin_amdgcn_s_setprio(1);
#pragma unroll
      for (int hh = 0; hh < 2; ++hh) {
        bfrag8 pa = *reinterpret_cast<const bfrag8*>(Pw + fr * PLDS + hh * 32 + kb * 8);
#pragma unroll
        for (int dt = 0; dt < 4; ++dt)
          acc[dt] = __builtin_amdgcn_mfma_f32_16x16x32_bf16(pa, vf[hh][dt], acc[dt], 0, 0, 0);
      }
      __builtin_amdgcn_s_setprio(0);
    }
  }

  // ---- 4-way merge ----
  if (wid > 0) {
#pragma unroll
    for (int dt = 0; dt < 4; ++dt)
#pragma unroll
      for (int j = 0; j < 4; ++j)
        ACCs[wid - 1][dt * 16 + rloc + j][fr] = acc[dt][j];
  }
  if (lane < 16) {
    MLs[wid][0][lane] = m_r;
    MLs[wid][1][lane] = l_r;
  }
  __syncthreads();
  if (wid == 0) {
#pragma unroll
    for (int j = 0; j < 4; ++j) {
      int row = rloc + j;
      float m0 = MLs[0][0][row], m1 = MLs[1][0][row];
      float m2 = MLs[2][0][row], m3 = MLs[3][0][row];
      float mm = fmaxf(fmaxf(m0, m1), fmaxf(m2, m3));
      float cw0 = exp2f(m0 - mm), cw1 = exp2f(m1 - mm);
      float cw2 = exp2f(m2 - mm), cw3 = exp2f(m3 - mm);
      float inv = 1.0f / (MLs[0][1][row] * cw0 + MLs[1][1][row] * cw1 +
                          MLs[2][1][row] * cw2 + MLs[3][1][row] * cw3);
      int grow = qrow0 + row;
#pragma unroll
      for (int dt = 0; dt < 4; ++dt) {
        float o = acc[dt][j] * cw0 + ACCs[0][dt * 16 + row][fr] * cw1 +
                  ACCs[1][dt * 16 + row][fr] * cw2 + ACCs[2][dt * 16 + row][fr] * cw3;
        aout[(size_t)grow * (NH * HDIM) + h * 64 + dt * 16 + fr] = f2bf(o * inv);
      }
    }
  }
}

// ---------------- launch ----------------
extern "C" void kernel_launch(void* const* d_in, const int* in_sizes, int n_in,
                              void* d_out, int out_size, void* d_ws, size_t ws_size,
                              hipStream_t stream) {
  const float* x    = (const float*)d_in[0];
  const float* pcos = (const float*)d_in[1];
  const float* psin = (const float*)d_in[2];
  const float* wqkv = (const float*)d_in[3];
  const float* wo   = (const float*)d_in[4];
  float* out = (float*)d_out;

  char* ws = (char*)d_ws;
  unsigned short* xb    = (unsigned short*)ws;  ws += (size_t)S_LEN * DMODEL * 2;
  unsigned short* wqkvT = (unsigned short*)ws;  ws += (size_t)NQKV * DMODEL * 2;
  unsigned short* woT   = (unsigned short*)ws;  ws += (size_t)DMODEL * DMODEL * 2;
  float*          qkv   = (float*)ws;           ws += (size_t)S_LEN * NQKV * 4;
  unsigned short* Qh    = (unsigned short*)ws;  ws += (size_t)NH * S_LEN * HDIM * 2;
  unsigned short* Kh    = (unsigned short*)ws;  ws += (size_t)NKV * S_LEN * HDIM * 2;
  unsigned short* Vt    = (unsigned short*)ws;  ws += (size_t)NKV * HDIM * S_LEN * 2;
  unsigned short* aoutb = (unsigned short*)ws;  ws += (size_t)S_LEN * NH * HDIM * 2;

  convert_bf16<<<(S_LEN * DMODEL) / (256 * 4), 256, 0, stream>>>(x, xb, S_LEN * DMODEL);
  transpose_convert<<<dim3(NQKV / 32, DMODEL / 32, 1), dim3(32, 8), 0, stream>>>(
      wqkv, NQKV, 0, wqkvT, DMODEL, 0, DMODEL, NQKV);
  transpose_convert<<<dim3(DMODEL / 32, DMODEL / 32, 1), dim3(32, 8), 0, stream>>>(
      wo, DMODEL, 0, woT, DMODEL, 0, DMODEL, DMODEL);
  gemm_bf16<<<dim3(S_LEN / BM, NQKV / BN), 256, 0, stream>>>(xb, wqkvT, qkv, S_LEN, NQKV, DMODEL);
  rope_kernel<<<S_LEN, 256, 0, stream>>>(qkv, pcos, psin, Qh, Kh);
  transpose_convert<<<dim3(HDIM / 32, S_LEN / 32, NKV), dim3(32, 8), 0, stream>>>(
      qkv + 1280, NQKV, 64, Vt, S_LEN, (long)HDIM * S_LEN, S_LEN, HDIM);
  flash_attn<<<dim3(256, NH), 256, 0, stream>>>(Qh, Kh, Vt, aoutb);
  gemm_bf16<<<dim3(S_LEN / BM, DMODEL / BN), 256, 0, stream>>>(aoutb, woT, out, S_LEN, DMODEL, DMODEL);
}

// Round 6
// 255.927 us; speedup vs baseline: 1.8275x; 1.4235x over previous
//
#include <hip/hip_runtime.h>

#define S_LEN 4096
#define DMODEL 1024
#define NH 16
#define NKV 4
#define HDIM 64
#define NQKV 1536  /* (16+2*4)*64 */

typedef __attribute__((ext_vector_type(8))) short bfrag8;
typedef __attribute__((ext_vector_type(4))) float f32x4_t;

__device__ __forceinline__ unsigned short f2bf(float f) {
  unsigned int u = __builtin_bit_cast(unsigned int, f);
  return (unsigned short)((u + 0x7fffu + ((u >> 16) & 1u)) >> 16);
}

// ---------------- elementwise f32 -> bf16 ----------------
__global__ void convert_bf16(const float* __restrict__ in, unsigned short* __restrict__ out, int n) {
  int idx = (blockIdx.x * 256 + threadIdx.x) * 4;
  if (idx < n) {
    float4 v = *reinterpret_cast<const float4*>(in + idx);
    out[idx + 0] = f2bf(v.x);
    out[idx + 1] = f2bf(v.y);
    out[idx + 2] = f2bf(v.z);
    out[idx + 3] = f2bf(v.w);
  }
}

// ---------------- tiled transpose + convert: out[c][r] = bf16(in[r][c]) ----------------
__global__ void transpose_convert(const float* __restrict__ in, int ldin, long in_zstride,
                                  unsigned short* __restrict__ out, int ldout, long out_zstride,
                                  int R, int C) {
  __shared__ float tile[32][33];
  const float* inb = in + (size_t)blockIdx.z * in_zstride;
  unsigned short* outb = out + (size_t)blockIdx.z * out_zstride;
  int c0 = blockIdx.x * 32, r0 = blockIdx.y * 32;
  int tx = threadIdx.x, ty = threadIdx.y;  // 32 x 8
  for (int i = 0; i < 4; ++i) {
    int r = r0 + ty + i * 8;
    tile[ty + i * 8][tx] = inb[(size_t)r * ldin + c0 + tx];
  }
  __syncthreads();
  for (int i = 0; i < 4; ++i) {
    int c = c0 + ty + i * 8;
    outb[(size_t)c * ldout + r0 + tx] = f2bf(tile[tx][ty + i * 8]);
  }
}

// ---------------- RoPE; Q pre-scaled by 0.125*log2(e) so QK^T lands in exp2 domain ----------------
__global__ void rope_kernel(const float* __restrict__ qkv,
                            const float* __restrict__ pcos, const float* __restrict__ psin,
                            unsigned short* __restrict__ Qh, unsigned short* __restrict__ Kh) {
  const float SCL = 0.125f * 1.44269504f;
  int s = blockIdx.x;
  int t = threadIdx.x;
  const float* row = qkv + (size_t)s * NQKV;
  for (int p = t; p < 640; p += 256) {
    int i = p & 31;
    float c = pcos[s * 32 + i], sn = psin[s * 32 + i];
    if (p < 512) {
      int h = p >> 5;
      float te = row[h * 64 + 2 * i], to = row[h * 64 + 2 * i + 1];
      size_t base = ((size_t)h * S_LEN + s) * 64;
      Qh[base + 2 * i]     = f2bf((te * c - to * sn) * SCL);
      Qh[base + 2 * i + 1] = f2bf((te * sn + to * c) * SCL);
    } else {
      int hk = (p - 512) >> 5;
      float te = row[1024 + hk * 64 + 2 * i], to = row[1024 + hk * 64 + 2 * i + 1];
      size_t base = ((size_t)hk * S_LEN + s) * 64;
      Kh[base + 2 * i]     = f2bf(te * c - to * sn);
      Kh[base + 2 * i + 1] = f2bf(te * sn + to * c);
    }
  }
}

// ---------------- bf16 MFMA GEMM: C(MxN,f32) = A(MxK) * Bt(NxK)^T ----------------
#define BM 128
#define BN 128
#define BK 32
#define LDSW 40

__global__ __launch_bounds__(256) void gemm_bf16(
    const unsigned short* __restrict__ A,
    const unsigned short* __restrict__ Bt,
    float* __restrict__ C, int M, int N, int K) {
  __shared__ unsigned short As[BM * LDSW];
  __shared__ unsigned short Bs[BN * LDSW];
  int m0 = blockIdx.x * BM, n0 = blockIdx.y * BN;
  int t = threadIdx.x, lane = t & 63, wid = t >> 6;
  int wm = (wid >> 1) * 64, wn = (wid & 1) * 64;
  int fr = lane & 15, kb = lane >> 4;
  f32x4_t acc[4][4];
  for (int r = 0; r < 4; ++r)
    for (int c = 0; c < 4; ++c) acc[r][c] = (f32x4_t){0.f, 0.f, 0.f, 0.f};

  for (int k0 = 0; k0 < K; k0 += BK) {
    __syncthreads();
    for (int i = 0; i < 2; ++i) {
      int idx = (i * 256 + t) * 8;
      int r = idx >> 5, c = idx & 31;
      bfrag8 va = *reinterpret_cast<const bfrag8*>(A + (size_t)(m0 + r) * K + k0 + c);
      *reinterpret_cast<bfrag8*>(&As[r * LDSW + c]) = va;
      bfrag8 vb = *reinterpret_cast<const bfrag8*>(Bt + (size_t)(n0 + r) * K + k0 + c);
      *reinterpret_cast<bfrag8*>(&Bs[r * LDSW + c]) = vb;
    }
    __syncthreads();
    bfrag8 af[4], bfr[4];
    for (int rb = 0; rb < 4; ++rb)
      af[rb] = *reinterpret_cast<const bfrag8*>(&As[(wm + rb * 16 + fr) * LDSW + kb * 8]);
    for (int cb = 0; cb < 4; ++cb)
      bfr[cb] = *reinterpret_cast<const bfrag8*>(&Bs[(wn + cb * 16 + fr) * LDSW + kb * 8]);
    for (int rb = 0; rb < 4; ++rb)
      for (int cb = 0; cb < 4; ++cb)
        acc[rb][cb] = __builtin_amdgcn_mfma_f32_16x16x32_bf16(af[rb], bfr[cb], acc[rb][cb], 0, 0, 0);
  }
  int rowg = (lane >> 4) * 4, colg = lane & 15;
  for (int rb = 0; rb < 4; ++rb)
    for (int cb = 0; cb < 4; ++cb)
      for (int j = 0; j < 4; ++j) {
        int r = m0 + wm + rb * 16 + rowg + j;
        int c = n0 + wn + cb * 16 + colg;
        C[(size_t)r * N + c] = acc[rb][cb][j];
      }
}

// ---------------- flash attention: causal, GQA, swapped-QK^T, 32 q-rows/wave ----------------
// Qh [NH][S][64] (pre-scaled), Kh [NKV][S][64], Vt [NKV][64][S], aout [S][NH*64] bf16
// Block: 256 thr = 4 waves = the 4 q-heads of one kv-group, same 32-row q-tile.
// Grid: 512 blocks (4 hk x 128 q-tiles); ALL 2048 waves co-resident -> makespan = longest wave.
// No cross-wave merge, no __syncthreads. P staged per-wave in LDS, 128B row + XOR swizzle.
__global__ __launch_bounds__(256, 2) void flash_attn(
    const unsigned short* __restrict__ Qh,
    const unsigned short* __restrict__ Kh,
    const unsigned short* __restrict__ Vt,
    unsigned short* __restrict__ aout) {
  __shared__ unsigned short Pl[4][32 * 64];  // 4 waves x 32 rows x 128B
  int bid = blockIdx.x;
  int hk = bid & 3;
  int qt = 127 - (bid >> 2);  // longest chains first
  int qrow0 = qt * 32;
  int t = threadIdx.x, lane = t & 63, wid = t >> 6;
  int head = hk * 4 + wid;
  int fr = lane & 15, kb = lane >> 4, rloc = kb * 4;
  char* Pw = (char*)&Pl[wid][0];
  int swz = (fr & 7) << 4;  // XOR key: row-dependent bank spread, bijective within 128B row

  // Q fragments: 2 row-groups x 2 k-halves
  const unsigned short* Qbase = Qh + ((size_t)head * S_LEN + qrow0) * 64;
  bfrag8 qf[2][2];
  qf[0][0] = *reinterpret_cast<const bfrag8*>(Qbase + fr * 64 + kb * 8);
  qf[0][1] = *reinterpret_cast<const bfrag8*>(Qbase + fr * 64 + 32 + kb * 8);
  qf[1][0] = *reinterpret_cast<const bfrag8*>(Qbase + (16 + fr) * 64 + kb * 8);
  qf[1][1] = *reinterpret_cast<const bfrag8*>(Qbase + (16 + fr) * 64 + 32 + kb * 8);

  // uniform bases + single per-lane offsets -> saddr-form loads, ~zero per-tile addr VALU
  const unsigned short* Kt = Kh + (size_t)hk * S_LEN * 64;
  const unsigned short* Vb = Vt + (size_t)hk * 64 * S_LEN;
  int koff = fr * 64 + kb * 8;
  int voff = fr * S_LEN + kb * 8;

  float m_r[2] = {-1e30f, -1e30f}, l_r[2] = {0.f, 0.f};
  f32x4_t acc[2][4];
#pragma unroll
  for (int g = 0; g < 2; ++g)
#pragma unroll
    for (int dt = 0; dt < 4; ++dt) acc[g][dt] = (f32x4_t){0.f, 0.f, 0.f, 0.f};

  int ntt = (qrow0 + 95) / 64;                          // total KV tiles
  int nf = (qrow0 >= 63) ? ((qrow0 - 63) / 64 + 1) : 0; // fully-unmasked tiles

  bfrag8 kf[4][2];
  {
    const unsigned short* K0 = Kt + koff;
#pragma unroll
    for (int ct = 0; ct < 4; ++ct) {
      kf[ct][0] = *reinterpret_cast<const bfrag8*>(K0 + ct * 1024);
      kf[ct][1] = *reinterpret_cast<const bfrag8*>(K0 + ct * 1024 + 32);
    }
  }

  for (int kt = 0; kt < ntt; ++kt) {
    int kv0 = kt * 64;
    // V loads (consumed by PV at bottom; wait hides behind QK+softmax)
    const unsigned short* Vtile = Vb + kv0 + voff;
    bfrag8 vf[2][4];
#pragma unroll
    for (int hh = 0; hh < 2; ++hh)
#pragma unroll
      for (int dt = 0; dt < 4; ++dt)
        vf[hh][dt] = *reinterpret_cast<const bfrag8*>(Vtile + dt * 16 * S_LEN + hh * 32);
    __builtin_amdgcn_sched_barrier(0);
    // swapped QK^T: lane (kb,fr) holds q-row (g*16+fr), k-cols ct*16+kb*4+j; 2 independent chains
    f32x4_t sc[2][4];
    __builtin_amdgcn_s_setprio(1);
#pragma unroll
    for (int ct = 0; ct < 4; ++ct) {
      f32x4_t z0 = (f32x4_t){0.f, 0.f, 0.f, 0.f};
      z0 = __builtin_amdgcn_mfma_f32_16x16x32_bf16(kf[ct][0], qf[0][0], z0, 0, 0, 0);
      sc[0][ct] = __builtin_amdgcn_mfma_f32_16x16x32_bf16(kf[ct][1], qf[0][1], z0, 0, 0, 0);
      f32x4_t z1 = (f32x4_t){0.f, 0.f, 0.f, 0.f};
      z1 = __builtin_amdgcn_mfma_f32_16x16x32_bf16(kf[ct][0], qf[1][0], z1, 0, 0, 0);
      sc[1][ct] = __builtin_amdgcn_mfma_f32_16x16x32_bf16(kf[ct][1], qf[1][1], z1, 0, 0, 0);
    }
    __builtin_amdgcn_s_setprio(0);
    // prefetch next tile's K now that QK consumed kf; softmax+PV cover the latency
    if (kt + 1 < ntt) {
      const unsigned short* Kn = Kt + (kv0 + 64) * 64 + koff;
#pragma unroll
      for (int ct = 0; ct < 4; ++ct) {
        kf[ct][0] = *reinterpret_cast<const bfrag8*>(Kn + ct * 1024);
        kf[ct][1] = *reinterpret_cast<const bfrag8*>(Kn + ct * 1024 + 32);
      }
    }
    __builtin_amdgcn_sched_barrier(0);
    if (kt >= nf) {
#pragma unroll
      for (int g = 0; g < 2; ++g) {
        int grow = qrow0 + g * 16 + fr;
#pragma unroll
        for (int ct = 0; ct < 4; ++ct)
#pragma unroll
          for (int j = 0; j < 4; ++j)
            sc[g][ct][j] = ((kv0 + ct * 16 + kb * 4 + j) <= grow) ? sc[g][ct][j] : -1e30f;
      }
    }
    // row max: nested-3 fmax trees (v_max3) + 2 shuffles, per group
    float pmax[2];
#pragma unroll
    for (int g = 0; g < 2; ++g) {
      float p0 = fmaxf(fmaxf(sc[g][0][0], sc[g][0][1]), fmaxf(sc[g][0][2], sc[g][0][3]));
      float p1 = fmaxf(fmaxf(sc[g][1][0], sc[g][1][1]), fmaxf(sc[g][1][2], sc[g][1][3]));
      float p2 = fmaxf(fmaxf(sc[g][2][0], sc[g][2][1]), fmaxf(sc[g][2][2], sc[g][2][3]));
      float p3 = fmaxf(fmaxf(sc[g][3][0], sc[g][3][1]), fmaxf(sc[g][3][2], sc[g][3][3]));
      float pm = fmaxf(fmaxf(p0, p1), fmaxf(p2, p3));
      pm = fmaxf(pm, __shfl_xor(pm, 16));
      pmax[g] = fmaxf(pm, __shfl_xor(pm, 32));
    }
    // defer-max: rescale only when a group's max rose by > 8 (exp2 domain)
    bool need = (pmax[0] > m_r[0] + 8.0f) || (pmax[1] > m_r[1] + 8.0f);
    if (__any(need)) {
#pragma unroll
      for (int g = 0; g < 2; ++g) {
        float mnew = fmaxf(m_r[g], pmax[g]);
        float a = exp2f(m_r[g] - mnew);
        l_r[g] *= a;
        m_r[g] = mnew;
#pragma unroll
        for (int j = 0; j < 4; ++j) {
          float aj = __shfl(a, rloc + j);
#pragma unroll
          for (int dt = 0; dt < 4; ++dt) acc[g][dt][j] *= aj;
        }
      }
    }
    // P = exp2(s - m); lane-local sums + 2 shuffles, per group
#pragma unroll
    for (int g = 0; g < 2; ++g) {
      float s = 0.f;
#pragma unroll
      for (int ct = 0; ct < 4; ++ct)
#pragma unroll
        for (int j = 0; j < 4; ++j) {
          float p = exp2f(sc[g][ct][j] - m_r[g]);
          sc[g][ct][j] = p;
          s += p;
        }
      s += __shfl_xor(s, 16);
      s += __shfl_xor(s, 32);
      l_r[g] += s;
    }
    // P -> per-wave LDS, swizzled packed b64 writes (row = g*16+fr, 128B rows)
#pragma unroll
    for (int g = 0; g < 2; ++g)
#pragma unroll
      for (int ct = 0; ct < 4; ++ct) {
        unsigned int u01 = (unsigned int)f2bf(sc[g][ct][0]) | ((unsigned int)f2bf(sc[g][ct][1]) << 16);
        unsigned int u23 = (unsigned int)f2bf(sc[g][ct][2]) | ((unsigned int)f2bf(sc[g][ct][3]) << 16);
        unsigned long long w = ((unsigned long long)u23 << 32) | u01;
        *reinterpret_cast<unsigned long long*>(
            Pw + (g * 16 + fr) * 128 + ((ct * 32 + kb * 8) ^ swz)) = w;
      }
    // PV: A = P (rows = q), B = V; 2 independent accumulation chains
    __builtin_amdgcn_s_setprio(1);
#pragma unroll
    for (int hh = 0; hh < 2; ++hh) {
      bfrag8 pa0 = *reinterpret_cast<const bfrag8*>(Pw + fr * 128 + ((hh * 64 + kb * 16) ^ swz));
      bfrag8 pa1 = *reinterpret_cast<const bfrag8*>(Pw + (16 + fr) * 128 + ((hh * 64 + kb * 16) ^ swz));
#pragma unroll
      for (int dt = 0; dt < 4; ++dt) {
        acc[0][dt] = __builtin_amdgcn_mfma_f32_16x16x32_bf16(pa0, vf[hh][dt], acc[0][dt], 0, 0, 0);
        acc[1][dt] = __builtin_amdgcn_mfma_f32_16x16x32_bf16(pa1, vf[hh][dt], acc[1][dt], 0, 0, 0);
      }
    }
    __builtin_amdgcn_s_setprio(0);
  }

  // epilogue: normalize and write 32 rows x 64 cols
#pragma unroll
  for (int g = 0; g < 2; ++g)
#pragma unroll
    for (int j = 0; j < 4; ++j) {
      float lj = __shfl(l_r[g], rloc + j);
      float inv = 1.0f / lj;
      int grow = qrow0 + g * 16 + rloc + j;
#pragma unroll
      for (int dt = 0; dt < 4; ++dt)
        aout[(size_t)grow * (NH * HDIM) + head * 64 + dt * 16 + fr] = f2bf(acc[g][dt][j] * inv);
    }
}

// ---------------- launch ----------------
extern "C" void kernel_launch(void* const* d_in, const int* in_sizes, int n_in,
                              void* d_out, int out_size, void* d_ws, size_t ws_size,
                              hipStream_t stream) {
  const float* x    = (const float*)d_in[0];
  const float* pcos = (const float*)d_in[1];
  const float* psin = (const float*)d_in[2];
  const float* wqkv = (const float*)d_in[3];
  const float* wo   = (const float*)d_in[4];
  float* out = (float*)d_out;

  char* ws = (char*)d_ws;
  unsigned short* xb    = (unsigned short*)ws;  ws += (size_t)S_LEN * DMODEL * 2;
  unsigned short* wqkvT = (unsigned short*)ws;  ws += (size_t)NQKV * DMODEL * 2;
  unsigned short* woT   = (unsigned short*)ws;  ws += (size_t)DMODEL * DMODEL * 2;
  float*          qkv   = (float*)ws;           ws += (size_t)S_LEN * NQKV * 4;
  unsigned short* Qh    = (unsigned short*)ws;  ws += (size_t)NH * S_LEN * HDIM * 2;
  unsigned short* Kh    = (unsigned short*)ws;  ws += (size_t)NKV * S_LEN * HDIM * 2;
  unsigned short* Vt    = (unsigned short*)ws;  ws += (size_t)NKV * HDIM * S_LEN * 2;
  unsigned short* aoutb = (unsigned short*)ws;  ws += (size_t)S_LEN * NH * HDIM * 2;

  convert_bf16<<<(S_LEN * DMODEL) / (256 * 4), 256, 0, stream>>>(x, xb, S_LEN * DMODEL);
  transpose_convert<<<dim3(NQKV / 32, DMODEL / 32, 1), dim3(32, 8), 0, stream>>>(
      wqkv, NQKV, 0, wqkvT, DMODEL, 0, DMODEL, NQKV);
  transpose_convert<<<dim3(DMODEL / 32, DMODEL / 32, 1), dim3(32, 8), 0, stream>>>(
      wo, DMODEL, 0, woT, DMODEL, 0, DMODEL, DMODEL);
  gemm_bf16<<<dim3(S_LEN / BM, NQKV / BN), 256, 0, stream>>>(xb, wqkvT, qkv, S_LEN, NQKV, DMODEL);
  rope_kernel<<<S_LEN, 256, 0, stream>>>(qkv, pcos, psin, Qh, Kh);
  transpose_convert<<<dim3(HDIM / 32, S_LEN / 32, NKV), dim3(32, 8), 0, stream>>>(
      qkv + 1280, NQKV, 64, Vt, S_LEN, (long)HDIM * S_LEN, S_LEN, HDIM);
  flash_attn<<<dim3(512), 256, 0, stream>>>(Qh, Kh, Vt, aoutb);
  gemm_bf16<<<dim3(S_LEN / BM, DMODEL / BN), 256, 0, stream>>>(aoutb, woT, out, S_LEN, DMODEL, DMODEL);
}

// Round 9
// 211.029 us; speedup vs baseline: 2.2163x; 1.2128x over previous
//
#include <hip/hip_runtime.h>

#define S_LEN 4096
#define DMODEL 1024
#define NH 16
#define NKV 4
#define HDIM 64
#define NQKV 1536  /* (16+2*4)*64 */

typedef __attribute__((ext_vector_type(8))) short bfrag8;
typedef __attribute__((ext_vector_type(4))) float f32x4_t;

__device__ __forceinline__ unsigned short f2bf(float f) {
  unsigned int u = __builtin_bit_cast(unsigned int, f);
  return (unsigned short)((u + 0x7fffu + ((u >> 16) & 1u)) >> 16);
}

// ---------------- elementwise f32 -> bf16 ----------------
__global__ void convert_bf16(const float* __restrict__ in, unsigned short* __restrict__ out, int n) {
  int idx = (blockIdx.x * 256 + threadIdx.x) * 4;
  if (idx < n) {
    float4 v = *reinterpret_cast<const float4*>(in + idx);
    out[idx + 0] = f2bf(v.x);
    out[idx + 1] = f2bf(v.y);
    out[idx + 2] = f2bf(v.z);
    out[idx + 3] = f2bf(v.w);
  }
}

// ---------------- tiled transpose + convert: out[c][r] = bf16(in[r][c]) ----------------
__global__ void transpose_convert(const float* __restrict__ in, int ldin, long in_zstride,
                                  unsigned short* __restrict__ out, int ldout, long out_zstride,
                                  int R, int C) {
  __shared__ float tile[32][33];
  const float* inb = in + (size_t)blockIdx.z * in_zstride;
  unsigned short* outb = out + (size_t)blockIdx.z * out_zstride;
  int c0 = blockIdx.x * 32, r0 = blockIdx.y * 32;
  int tx = threadIdx.x, ty = threadIdx.y;  // 32 x 8
  for (int i = 0; i < 4; ++i) {
    int r = r0 + ty + i * 8;
    tile[ty + i * 8][tx] = inb[(size_t)r * ldin + c0 + tx];
  }
  __syncthreads();
  for (int i = 0; i < 4; ++i) {
    int c = c0 + ty + i * 8;
    outb[(size_t)c * ldout + r0 + tx] = f2bf(tile[tx][ty + i * 8]);
  }
}

// ---------------- RoPE; Q pre-scaled by 0.125*log2(e) so QK^T lands in exp2 domain ----------------
__global__ void rope_kernel(const float* __restrict__ qkv,
                            const float* __restrict__ pcos, const float* __restrict__ psin,
                            unsigned short* __restrict__ Qh, unsigned short* __restrict__ Kh) {
  const float SCL = 0.125f * 1.44269504f;
  int s = blockIdx.x;
  int t = threadIdx.x;
  const float* row = qkv + (size_t)s * NQKV;
  for (int p = t; p < 640; p += 256) {
    int i = p & 31;
    float c = pcos[s * 32 + i], sn = psin[s * 32 + i];
    if (p < 512) {
      int h = p >> 5;
      float te = row[h * 64 + 2 * i], to = row[h * 64 + 2 * i + 1];
      size_t base = ((size_t)h * S_LEN + s) * 64;
      Qh[base + 2 * i]     = f2bf((te * c - to * sn) * SCL);
      Qh[base + 2 * i + 1] = f2bf((te * sn + to * c) * SCL);
    } else {
      int hk = (p - 512) >> 5;
      float te = row[1024 + hk * 64 + 2 * i], to = row[1024 + hk * 64 + 2 * i + 1];
      size_t base = ((size_t)hk * S_LEN + s) * 64;
      Kh[base + 2 * i]     = f2bf(te * c - to * sn);
      Kh[base + 2 * i + 1] = f2bf(te * sn + to * c);
    }
  }
}

// ---------------- bf16 MFMA GEMM (R5-proven): C(MxN,f32) = A(MxK) * Bt(NxK)^T ----------------
#define BM 128
#define BN 128
#define BK 32
#define LDSW 40

__global__ __launch_bounds__(256) void gemm_bf16(
    const unsigned short* __restrict__ A,
    const unsigned short* __restrict__ Bt,
    float* __restrict__ C, int M, int N, int K) {
  __shared__ unsigned short As[BM * LDSW];
  __shared__ unsigned short Bs[BN * LDSW];
  int m0 = blockIdx.x * BM, n0 = blockIdx.y * BN;
  int t = threadIdx.x, lane = t & 63, wid = t >> 6;
  int wm = (wid >> 1) * 64, wn = (wid & 1) * 64;
  int fr = lane & 15, kb = lane >> 4;
  f32x4_t acc[4][4];
  for (int r = 0; r < 4; ++r)
    for (int c = 0; c < 4; ++c) acc[r][c] = (f32x4_t){0.f, 0.f, 0.f, 0.f};

  for (int k0 = 0; k0 < K; k0 += BK) {
    __syncthreads();
    for (int i = 0; i < 2; ++i) {
      int idx = (i * 256 + t) * 8;
      int r = idx >> 5, c = idx & 31;
      bfrag8 va = *reinterpret_cast<const bfrag8*>(A + (size_t)(m0 + r) * K + k0 + c);
      *reinterpret_cast<bfrag8*>(&As[r * LDSW + c]) = va;
      bfrag8 vb = *reinterpret_cast<const bfrag8*>(Bt + (size_t)(n0 + r) * K + k0 + c);
      *reinterpret_cast<bfrag8*>(&Bs[r * LDSW + c]) = vb;
    }
    __syncthreads();
    bfrag8 af[4], bfr[4];
    for (int rb = 0; rb < 4; ++rb)
      af[rb] = *reinterpret_cast<const bfrag8*>(&As[(wm + rb * 16 + fr) * LDSW + kb * 8]);
    for (int cb = 0; cb < 4; ++cb)
      bfr[cb] = *reinterpret_cast<const bfrag8*>(&Bs[(wn + cb * 16 + fr) * LDSW + kb * 8]);
    for (int rb = 0; rb < 4; ++rb)
      for (int cb = 0; cb < 4; ++cb)
        acc[rb][cb] = __builtin_amdgcn_mfma_f32_16x16x32_bf16(af[rb], bfr[cb], acc[rb][cb], 0, 0, 0);
  }
  int rowg = (lane >> 4) * 4, colg = lane & 15;
  for (int rb = 0; rb < 4; ++rb)
    for (int cb = 0; cb < 4; ++cb)
      for (int j = 0; j < 4; ++j) {
        int r = m0 + wm + rb * 16 + rowg + j;
        int c = n0 + wn + cb * 16 + colg;
        C[(size_t)r * N + c] = acc[rb][cb][j];
      }
}

// ---------------- flash attention: causal, GQA, swapped-QK^T, 32 q-rows/wave, 4-way KV split ----------------
// Qh [NH][S][64] (pre-scaled), Kh [NKV][S][64], Vt [NKV][64][S], aout [S][NH*64] bf16
// Block: 256 thr = 4 waves; all 4 waves share one (head, 32-row q-tile), each takes 1/4 of KV range.
// Grid: 2048 blocks (16 heads x 128 q-tiles, longest-first). In-block log-tree merge via LDS.
// MERGE NOTE: m_r/l_r live on lane fr (per q-row g*16+fr); acc[g][dt][j] holds q-row g*16+rloc+j.
// Any scale derived from m/l MUST be broadcast via __shfl(x, rloc+j) before touching acc. (R7 bug.)
__global__ __launch_bounds__(256) void flash_attn(
    const unsigned short* __restrict__ Qh,
    const unsigned short* __restrict__ Kh,
    const unsigned short* __restrict__ Vt,
    unsigned short* __restrict__ aout) {
  __shared__ __align__(16) char SMEM[18432];  // union: Pl[4][4KB] | 2 x merge region [36][64] f32
  int bid = blockIdx.x;
  int head = bid & 15, hk = head >> 2;
  int qt = 127 - (bid >> 4);  // longest chains dispatch first
  int qrow0 = qt * 32;
  int t = threadIdx.x, lane = t & 63, wid = t >> 6;
  int fr = lane & 15, kb = lane >> 4, rloc = kb * 4;
  char* Pw = SMEM + wid * 4096;
  int swz = (fr & 7) << 4;  // XOR swizzle within 128B P rows

  // Q fragments: 2 row-groups x 2 k-halves
  const unsigned short* Qbase = Qh + ((size_t)head * S_LEN + qrow0) * 64;
  bfrag8 qf[2][2];
  qf[0][0] = *reinterpret_cast<const bfrag8*>(Qbase + fr * 64 + kb * 8);
  qf[0][1] = *reinterpret_cast<const bfrag8*>(Qbase + fr * 64 + 32 + kb * 8);
  qf[1][0] = *reinterpret_cast<const bfrag8*>(Qbase + (16 + fr) * 64 + kb * 8);
  qf[1][1] = *reinterpret_cast<const bfrag8*>(Qbase + (16 + fr) * 64 + 32 + kb * 8);

  const unsigned short* Kt = Kh + (size_t)hk * S_LEN * 64;
  const unsigned short* Vb = Vt + (size_t)hk * 64 * S_LEN;
  int koff = fr * 64 + kb * 8;
  int voff = fr * S_LEN + kb * 8;

  float m_r[2] = {-1e30f, -1e30f}, l_r[2] = {0.f, 0.f};
  f32x4_t acc[2][4];
#pragma unroll
  for (int g = 0; g < 2; ++g)
#pragma unroll
    for (int dt = 0; dt < 4; ++dt) acc[g][dt] = (f32x4_t){0.f, 0.f, 0.f, 0.f};

  int ntt = (qrow0 + 95) / 64;                          // total KV tiles for this q-tile
  int nf = (qrow0 >= 63) ? ((qrow0 - 63) / 64 + 1) : 0; // fully-unmasked tiles
  int c0 = (wid * ntt) >> 2, c1 = ((wid + 1) * ntt) >> 2;

  if (c0 < c1) {
    bfrag8 kf[4][2];
    {
      const unsigned short* K0 = Kt + c0 * 64 * 64 + koff;
#pragma unroll
      for (int ct = 0; ct < 4; ++ct) {
        kf[ct][0] = *reinterpret_cast<const bfrag8*>(K0 + ct * 1024);
        kf[ct][1] = *reinterpret_cast<const bfrag8*>(K0 + ct * 1024 + 32);
      }
    }
    for (int kt = c0; kt < c1; ++kt) {
      int kv0 = kt * 64;
      // V loads (consumed by PV at bottom; wait hides behind QK+softmax)
      const unsigned short* Vtile = Vb + kv0 + voff;
      bfrag8 vf[2][4];
#pragma unroll
      for (int hh = 0; hh < 2; ++hh)
#pragma unroll
        for (int dt = 0; dt < 4; ++dt)
          vf[hh][dt] = *reinterpret_cast<const bfrag8*>(Vtile + dt * 16 * S_LEN + hh * 32);
      __builtin_amdgcn_sched_barrier(0);
      // swapped QK^T: lane (kb,fr) holds q-row (g*16+fr), k-cols ct*16+kb*4+j
      f32x4_t sc[2][4];
      __builtin_amdgcn_s_setprio(1);
#pragma unroll
      for (int ct = 0; ct < 4; ++ct) {
        f32x4_t z0 = (f32x4_t){0.f, 0.f, 0.f, 0.f};
        z0 = __builtin_amdgcn_mfma_f32_16x16x32_bf16(kf[ct][0], qf[0][0], z0, 0, 0, 0);
        sc[0][ct] = __builtin_amdgcn_mfma_f32_16x16x32_bf16(kf[ct][1], qf[0][1], z0, 0, 0, 0);
        f32x4_t z1 = (f32x4_t){0.f, 0.f, 0.f, 0.f};
        z1 = __builtin_amdgcn_mfma_f32_16x16x32_bf16(kf[ct][0], qf[1][0], z1, 0, 0, 0);
        sc[1][ct] = __builtin_amdgcn_mfma_f32_16x16x32_bf16(kf[ct][1], qf[1][1], z1, 0, 0, 0);
      }
      __builtin_amdgcn_s_setprio(0);
      // prefetch next tile's K now that QK consumed kf
      if (kt + 1 < c1) {
        const unsigned short* Kn = Kt + (kv0 + 64) * 64 + koff;
#pragma unroll
        for (int ct = 0; ct < 4; ++ct) {
          kf[ct][0] = *reinterpret_cast<const bfrag8*>(Kn + ct * 1024);
          kf[ct][1] = *reinterpret_cast<const bfrag8*>(Kn + ct * 1024 + 32);
        }
      }
      __builtin_amdgcn_sched_barrier(0);
      if (kt >= nf) {
#pragma unroll
        for (int g = 0; g < 2; ++g) {
          int grow = qrow0 + g * 16 + fr;
#pragma unroll
          for (int ct = 0; ct < 4; ++ct)
#pragma unroll
            for (int j = 0; j < 4; ++j)
              sc[g][ct][j] = ((kv0 + ct * 16 + kb * 4 + j) <= grow) ? sc[g][ct][j] : -1e30f;
        }
      }
      // row max: lane-local trees + 2 shuffles
      float pmax[2];
#pragma unroll
      for (int g = 0; g < 2; ++g) {
        float p0 = fmaxf(fmaxf(sc[g][0][0], sc[g][0][1]), fmaxf(sc[g][0][2], sc[g][0][3]));
        float p1 = fmaxf(fmaxf(sc[g][1][0], sc[g][1][1]), fmaxf(sc[g][1][2], sc[g][1][3]));
        float p2 = fmaxf(fmaxf(sc[g][2][0], sc[g][2][1]), fmaxf(sc[g][2][2], sc[g][2][3]));
        float p3 = fmaxf(fmaxf(sc[g][3][0], sc[g][3][1]), fmaxf(sc[g][3][2], sc[g][3][3]));
        float pm = fmaxf(fmaxf(p0, p1), fmaxf(p2, p3));
        pm = fmaxf(pm, __shfl_xor(pm, 16));
        pmax[g] = fmaxf(pm, __shfl_xor(pm, 32));
      }
      // defer-max: rescale only when a group's max rose by > 8 (exp2 domain)
      bool need = (pmax[0] > m_r[0] + 8.0f) || (pmax[1] > m_r[1] + 8.0f);
      if (__any(need)) {
#pragma unroll
        for (int g = 0; g < 2; ++g) {
          float mnew = fmaxf(m_r[g], pmax[g]);
          float a = exp2f(m_r[g] - mnew);
          l_r[g] *= a;
          m_r[g] = mnew;
#pragma unroll
          for (int j = 0; j < 4; ++j) {
            float aj = __shfl(a, rloc + j);
#pragma unroll
            for (int dt = 0; dt < 4; ++dt) acc[g][dt][j] *= aj;
          }
        }
      }
      // P = exp2(s - m); lane-local sums + 2 shuffles
#pragma unroll
      for (int g = 0; g < 2; ++g) {
        float s = 0.f;
#pragma unroll
        for (int ct = 0; ct < 4; ++ct)
#pragma unroll
          for (int j = 0; j < 4; ++j) {
            float p = exp2f(sc[g][ct][j] - m_r[g]);
            sc[g][ct][j] = p;
            s += p;
          }
        s += __shfl_xor(s, 16);
        s += __shfl_xor(s, 32);
        l_r[g] += s;
      }
      // P -> per-wave LDS, swizzled packed b64 writes (f2bf RNE bit-math)
#pragma unroll
      for (int g = 0; g < 2; ++g)
#pragma unroll
        for (int ct = 0; ct < 4; ++ct) {
          unsigned int u01 = (unsigned int)f2bf(sc[g][ct][0]) | ((unsigned int)f2bf(sc[g][ct][1]) << 16);
          unsigned int u23 = (unsigned int)f2bf(sc[g][ct][2]) | ((unsigned int)f2bf(sc[g][ct][3]) << 16);
          unsigned long long w = ((unsigned long long)u23 << 32) | u01;
          *reinterpret_cast<unsigned long long*>(
              Pw + (g * 16 + fr) * 128 + ((ct * 32 + kb * 8) ^ swz)) = w;
        }
      // PV: A = P (rows = q), B = V
      __builtin_amdgcn_s_setprio(1);
#pragma unroll
      for (int hh = 0; hh < 2; ++hh) {
        bfrag8 pa0 = *reinterpret_cast<const bfrag8*>(Pw + fr * 128 + ((hh * 64 + kb * 16) ^ swz));
        bfrag8 pa1 = *reinterpret_cast<const bfrag8*>(Pw + (16 + fr) * 128 + ((hh * 64 + kb * 16) ^ swz));
#pragma unroll
        for (int dt = 0; dt < 4; ++dt) {
          acc[0][dt] = __builtin_amdgcn_mfma_f32_16x16x32_bf16(pa0, vf[hh][dt], acc[0][dt], 0, 0, 0);
          acc[1][dt] = __builtin_amdgcn_mfma_f32_16x16x32_bf16(pa1, vf[hh][dt], acc[1][dt], 0, 0, 0);
        }
      }
      __builtin_amdgcn_s_setprio(0);
    }
  }

  // ---- log-tree merge: (0<-1, 2<-3) then (0<-2). Regions reuse P LDS. ----
  float* stgA = (float*)SMEM;
  float* stgB = (float*)(SMEM + 9216);
  __syncthreads();
  if (wid == 1 || wid == 3) {
    float* R = (wid == 1) ? stgA : stgB;
#pragma unroll
    for (int g = 0; g < 2; ++g) {
#pragma unroll
      for (int dt = 0; dt < 4; ++dt)
#pragma unroll
        for (int j = 0; j < 4; ++j)
          R[(g * 16 + dt * 4 + j) * 64 + lane] = acc[g][dt][j];
      R[(32 + g * 2) * 64 + lane] = m_r[g];
      R[(33 + g * 2) * 64 + lane] = l_r[g];
    }
  }
  __syncthreads();
  if (wid == 0 || wid == 2) {
    float* R = (wid == 0) ? stgA : stgB;
#pragma unroll
    for (int g = 0; g < 2; ++g) {
      float mo = R[(32 + g * 2) * 64 + lane], lo = R[(33 + g * 2) * 64 + lane];
      float mm = fmaxf(m_r[g], mo);
      float ca = exp2f(m_r[g] - mm), cb = exp2f(mo - mm);
      l_r[g] = l_r[g] * ca + lo * cb;
      m_r[g] = mm;
#pragma unroll
      for (int j = 0; j < 4; ++j) {
        float caj = __shfl(ca, rloc + j);   // row-matched factors (R7 fix)
        float cbj = __shfl(cb, rloc + j);
#pragma unroll
        for (int dt = 0; dt < 4; ++dt)
          acc[g][dt][j] = acc[g][dt][j] * caj + R[(g * 16 + dt * 4 + j) * 64 + lane] * cbj;
      }
    }
    if (wid == 2) {
#pragma unroll
      for (int g = 0; g < 2; ++g) {
#pragma unroll
        for (int dt = 0; dt < 4; ++dt)
#pragma unroll
          for (int j = 0; j < 4; ++j)
            stgB[(g * 16 + dt * 4 + j) * 64 + lane] = acc[g][dt][j];
        stgB[(32 + g * 2) * 64 + lane] = m_r[g];
        stgB[(33 + g * 2) * 64 + lane] = l_r[g];
      }
    }
  }
  __syncthreads();
  if (wid == 0) {
#pragma unroll
    for (int g = 0; g < 2; ++g) {
      float mo = stgB[(32 + g * 2) * 64 + lane], lo = stgB[(33 + g * 2) * 64 + lane];
      float mm = fmaxf(m_r[g], mo);
      float ca = exp2f(m_r[g] - mm), cb = exp2f(mo - mm);
      l_r[g] = l_r[g] * ca + lo * cb;
#pragma unroll
      for (int j = 0; j < 4; ++j) {
        float caj = __shfl(ca, rloc + j);   // row-matched factors (R7 fix)
        float cbj = __shfl(cb, rloc + j);
#pragma unroll
        for (int dt = 0; dt < 4; ++dt)
          acc[g][dt][j] = acc[g][dt][j] * caj + stgB[(g * 16 + dt * 4 + j) * 64 + lane] * cbj;
      }
    }
    // normalize and write 32 rows x 64 cols
#pragma unroll
    for (int g = 0; g < 2; ++g)
#pragma unroll
      for (int j = 0; j < 4; ++j) {
        float lj = __shfl(l_r[g], rloc + j);
        float inv = 1.0f / lj;
        int grow = qrow0 + g * 16 + rloc + j;
#pragma unroll
        for (int dt = 0; dt < 4; ++dt)
          aout[(size_t)grow * (NH * HDIM) + head * 64 + dt * 16 + fr] = f2bf(acc[g][dt][j] * inv);
      }
  }
}

// ---------------- launch ----------------
extern "C" void kernel_launch(void* const* d_in, const int* in_sizes, int n_in,
                              void* d_out, int out_size, void* d_ws, size_t ws_size,
                              hipStream_t stream) {
  const float* x    = (const float*)d_in[0];
  const float* pcos = (const float*)d_in[1];
  const float* psin = (const float*)d_in[2];
  const float* wqkv = (const float*)d_in[3];
  const float* wo   = (const float*)d_in[4];
  float* out = (float*)d_out;

  char* ws = (char*)d_ws;
  unsigned short* xb    = (unsigned short*)ws;  ws += (size_t)S_LEN * DMODEL * 2;
  unsigned short* wqkvT = (unsigned short*)ws;  ws += (size_t)NQKV * DMODEL * 2;
  unsigned short* woT   = (unsigned short*)ws;  ws += (size_t)DMODEL * DMODEL * 2;
  float*          qkv   = (float*)ws;           ws += (size_t)S_LEN * NQKV * 4;
  unsigned short* Qh    = (unsigned short*)ws;  ws += (size_t)NH * S_LEN * HDIM * 2;
  unsigned short* Kh    = (unsigned short*)ws;  ws += (size_t)NKV * S_LEN * HDIM * 2;
  unsigned short* Vt    = (unsigned short*)ws;  ws += (size_t)NKV * HDIM * S_LEN * 2;
  unsigned short* aoutb = (unsigned short*)ws;  ws += (size_t)S_LEN * NH * HDIM * 2;

  convert_bf16<<<(S_LEN * DMODEL) / (256 * 4), 256, 0, stream>>>(x, xb, S_LEN * DMODEL);
  transpose_convert<<<dim3(NQKV / 32, DMODEL / 32, 1), dim3(32, 8), 0, stream>>>(
      wqkv, NQKV, 0, wqkvT, DMODEL, 0, DMODEL, NQKV);
  transpose_convert<<<dim3(DMODEL / 32, DMODEL / 32, 1), dim3(32, 8), 0, stream>>>(
      wo, DMODEL, 0, woT, DMODEL, 0, DMODEL, DMODEL);
  gemm_bf16<<<dim3(S_LEN / BM, NQKV / BN), 256, 0, stream>>>(xb, wqkvT, qkv, S_LEN, NQKV, DMODEL);
  rope_kernel<<<S_LEN, 256, 0, stream>>>(qkv, pcos, psin, Qh, Kh);
  transpose_convert<<<dim3(HDIM / 32, S_LEN / 32, NKV), dim3(32, 8), 0, stream>>>(
      qkv + 1280, NQKV, 64, Vt, S_LEN, (long)HDIM * S_LEN, S_LEN, HDIM);
  flash_attn<<<dim3(2048), 256, 0, stream>>>(Qh, Kh, Vt, aoutb);
  gemm_bf16<<<dim3(S_LEN / BM, DMODEL / BN), 256, 0, stream>>>(aoutb, woT, out, S_LEN, DMODEL, DMODEL);
}

// Round 10
// 205.582 us; speedup vs baseline: 2.2750x; 1.0265x over previous
//
#include <hip/hip_runtime.h>

#define S_LEN 4096
#define DMODEL 1024
#define NH 16
#define NKV 4
#define HDIM 64
#define NQKV 1536  /* (16+2*4)*64 */

typedef __attribute__((ext_vector_type(8))) short bfrag8;
typedef __attribute__((ext_vector_type(4))) float f32x4_t;

__device__ __forceinline__ unsigned short f2bf(float f) {
  unsigned int u = __builtin_bit_cast(unsigned int, f);
  return (unsigned short)((u + 0x7fffu + ((u >> 16) & 1u)) >> 16);
}

// packed f32x2 -> bf16x2, single HW instruction (proven innocent in R6/R7 bisection)
__device__ __forceinline__ unsigned int cvtpk_bf16(float lo, float hi) {
  unsigned int r;
  asm("v_cvt_pk_bf16_f32 %0, %1, %2" : "=v"(r) : "v"(lo), "v"(hi));
  return r;
}

typedef __attribute__((address_space(3))) unsigned char lds_uc;
typedef const __attribute__((address_space(1))) unsigned char glob_uc;
__device__ __forceinline__ void gl16(const void* g, void* l) {
  __builtin_amdgcn_global_load_lds((glob_uc*)g, (lds_uc*)l, 16, 0, 0);
}

// ---------------- elementwise f32 -> bf16 ----------------
__global__ void convert_bf16(const float* __restrict__ in, unsigned short* __restrict__ out, int n) {
  int idx = (blockIdx.x * 256 + threadIdx.x) * 4;
  if (idx < n) {
    float4 v = *reinterpret_cast<const float4*>(in + idx);
    out[idx + 0] = f2bf(v.x);
    out[idx + 1] = f2bf(v.y);
    out[idx + 2] = f2bf(v.z);
    out[idx + 3] = f2bf(v.w);
  }
}

// ---------------- tiled transpose + convert: out[c][r] = bf16(in[r][c]) ----------------
__global__ void transpose_convert(const float* __restrict__ in, int ldin, long in_zstride,
                                  unsigned short* __restrict__ out, int ldout, long out_zstride,
                                  int R, int C) {
  __shared__ float tile[32][33];
  const float* inb = in + (size_t)blockIdx.z * in_zstride;
  unsigned short* outb = out + (size_t)blockIdx.z * out_zstride;
  int c0 = blockIdx.x * 32, r0 = blockIdx.y * 32;
  int tx = threadIdx.x, ty = threadIdx.y;  // 32 x 8
  for (int i = 0; i < 4; ++i) {
    int r = r0 + ty + i * 8;
    tile[ty + i * 8][tx] = inb[(size_t)r * ldin + c0 + tx];
  }
  __syncthreads();
  for (int i = 0; i < 4; ++i) {
    int c = c0 + ty + i * 8;
    outb[(size_t)c * ldout + r0 + tx] = f2bf(tile[tx][ty + i * 8]);
  }
}

// ---------------- RoPE; Q pre-scaled by 0.125*log2(e) so QK^T lands in exp2 domain ----------------
__global__ void rope_kernel(const float* __restrict__ qkv,
                            const float* __restrict__ pcos, const float* __restrict__ psin,
                            unsigned short* __restrict__ Qh, unsigned short* __restrict__ Kh) {
  const float SCL = 0.125f * 1.44269504f;
  int s = blockIdx.x;
  int t = threadIdx.x;
  const float* row = qkv + (size_t)s * NQKV;
  for (int p = t; p < 640; p += 256) {
    int i = p & 31;
    float c = pcos[s * 32 + i], sn = psin[s * 32 + i];
    if (p < 512) {
      int h = p >> 5;
      float te = row[h * 64 + 2 * i], to = row[h * 64 + 2 * i + 1];
      size_t base = ((size_t)h * S_LEN + s) * 64;
      Qh[base + 2 * i]     = f2bf((te * c - to * sn) * SCL);
      Qh[base + 2 * i + 1] = f2bf((te * sn + to * c) * SCL);
    } else {
      int hk = (p - 512) >> 5;
      float te = row[1024 + hk * 64 + 2 * i], to = row[1024 + hk * 64 + 2 * i + 1];
      size_t base = ((size_t)hk * S_LEN + s) * 64;
      Kh[base + 2 * i]     = f2bf(te * c - to * sn);
      Kh[base + 2 * i + 1] = f2bf(te * sn + to * c);
    }
  }
}

// ---------------- bf16 MFMA GEMM (m97 structure, proven innocent): C = A(MxK) * Bt(NxK)^T ----------------
// global_load_lds width-16 staging, linear LDS [128][32], 2 barriers / K-step.
__global__ __launch_bounds__(256) void gemm_bf16(
    const unsigned short* __restrict__ A,
    const unsigned short* __restrict__ Bt,
    float* __restrict__ C, int M, int N, int K) {
  __shared__ __align__(16) unsigned short As[128 * 32];
  __shared__ __align__(16) unsigned short Bs[128 * 32];
  int m0 = blockIdx.x * 128, n0 = blockIdx.y * 128;
  int t = threadIdx.x, lane = t & 63, wid = t >> 6;
  int wm = (wid >> 1) * 64, wn = (wid & 1) * 64;
  int fr = lane & 15, kb = lane >> 4;
  // staging: thread t -> row t/4, cols (t%4)*8..+7 ; LDS byte dest = t*16 (linear lane match)
  int srow = t >> 2, scol = (t & 3) * 8;
  const unsigned short* Ag0 = A + (size_t)(m0 + srow) * K + scol;
  const unsigned short* Ag1 = A + (size_t)(m0 + 64 + srow) * K + scol;
  const unsigned short* Bg0 = Bt + (size_t)(n0 + srow) * K + scol;
  const unsigned short* Bg1 = Bt + (size_t)(n0 + 64 + srow) * K + scol;
  char* AsW0 = (char*)As + wid * 1024;
  char* AsW1 = (char*)As + 4096 + wid * 1024;
  char* BsW0 = (char*)Bs + wid * 1024;
  char* BsW1 = (char*)Bs + 4096 + wid * 1024;

  f32x4_t acc[4][4];
#pragma unroll
  for (int r = 0; r < 4; ++r)
#pragma unroll
    for (int c = 0; c < 4; ++c) acc[r][c] = (f32x4_t){0.f, 0.f, 0.f, 0.f};

  for (int k0 = 0; k0 < K; k0 += 32) {
    __syncthreads();
    gl16(Ag0 + k0, AsW0);
    gl16(Ag1 + k0, AsW1);
    gl16(Bg0 + k0, BsW0);
    gl16(Bg1 + k0, BsW1);
    __syncthreads();
    bfrag8 af[4], bfr[4];
#pragma unroll
    for (int rb = 0; rb < 4; ++rb)
      af[rb] = *reinterpret_cast<const bfrag8*>(&As[(wm + rb * 16 + fr) * 32 + kb * 8]);
#pragma unroll
    for (int cb = 0; cb < 4; ++cb)
      bfr[cb] = *reinterpret_cast<const bfrag8*>(&Bs[(wn + cb * 16 + fr) * 32 + kb * 8]);
#pragma unroll
    for (int rb = 0; rb < 4; ++rb)
#pragma unroll
      for (int cb = 0; cb < 4; ++cb)
        acc[rb][cb] = __builtin_amdgcn_mfma_f32_16x16x32_bf16(af[rb], bfr[cb], acc[rb][cb], 0, 0, 0);
  }
  int rowg = (lane >> 4) * 4, colg = lane & 15;
#pragma unroll
  for (int rb = 0; rb < 4; ++rb)
#pragma unroll
    for (int cb = 0; cb < 4; ++cb)
#pragma unroll
      for (int j = 0; j < 4; ++j) {
        int r = m0 + wm + rb * 16 + rowg + j;
        int c = n0 + wn + cb * 16 + colg;
        C[(size_t)r * N + c] = acc[rb][cb][j];
      }
}

// ---------------- flash attention: causal, GQA, swapped-QK^T, 32 q-rows/wave, 4-way KV split ----------------
// Qh [NH][S][64] (pre-scaled), Kh [NKV][S][64], Vt [NKV][64][S], aout [S][NH*64] bf16
// Block: 256 thr = 4 waves; all 4 waves share one (head, 32-row q-tile), each takes 1/4 of KV range.
// Grid: 2048 blocks (16 heads x 128 q-tiles, longest-first). In-block log-tree merge via LDS.
// MERGE NOTE: m_r/l_r live on lane fr (per q-row g*16+fr); acc[g][dt][j] holds q-row g*16+rloc+j.
// Any scale derived from m/l MUST be broadcast via __shfl(x, rloc+j) before touching acc. (R7 bug.)
__global__ __launch_bounds__(256) void flash_attn(
    const unsigned short* __restrict__ Qh,
    const unsigned short* __restrict__ Kh,
    const unsigned short* __restrict__ Vt,
    unsigned short* __restrict__ aout) {
  __shared__ __align__(16) char SMEM[18432];  // union: Pl[4][4KB] | 2 x merge region [36][64] f32
  int bid = blockIdx.x;
  int head = bid & 15, hk = head >> 2;
  int qt = 127 - (bid >> 4);  // longest chains dispatch first
  int qrow0 = qt * 32;
  int t = threadIdx.x, lane = t & 63, wid = t >> 6;
  int fr = lane & 15, kb = lane >> 4, rloc = kb * 4;
  char* Pw = SMEM + wid * 4096;
  int swz = (fr & 7) << 4;  // XOR swizzle within 128B P rows

  // Q fragments: 2 row-groups x 2 k-halves
  const unsigned short* Qbase = Qh + ((size_t)head * S_LEN + qrow0) * 64;
  bfrag8 qf[2][2];
  qf[0][0] = *reinterpret_cast<const bfrag8*>(Qbase + fr * 64 + kb * 8);
  qf[0][1] = *reinterpret_cast<const bfrag8*>(Qbase + fr * 64 + 32 + kb * 8);
  qf[1][0] = *reinterpret_cast<const bfrag8*>(Qbase + (16 + fr) * 64 + kb * 8);
  qf[1][1] = *reinterpret_cast<const bfrag8*>(Qbase + (16 + fr) * 64 + 32 + kb * 8);

  const unsigned short* Kt = Kh + (size_t)hk * S_LEN * 64;
  const unsigned short* Vb = Vt + (size_t)hk * 64 * S_LEN;
  int koff = fr * 64 + kb * 8;
  int voff = fr * S_LEN + kb * 8;

  float m_r[2] = {-1e30f, -1e30f}, l_r[2] = {0.f, 0.f};
  f32x4_t acc[2][4];
#pragma unroll
  for (int g = 0; g < 2; ++g)
#pragma unroll
    for (int dt = 0; dt < 4; ++dt) acc[g][dt] = (f32x4_t){0.f, 0.f, 0.f, 0.f};

  int ntt = (qrow0 + 95) / 64;                          // total KV tiles for this q-tile
  int nf = (qrow0 >= 63) ? ((qrow0 - 63) / 64 + 1) : 0; // fully-unmasked tiles
  int c0 = (wid * ntt) >> 2, c1 = ((wid + 1) * ntt) >> 2;

  if (c0 < c1) {
    bfrag8 kf[4][2];
    {
      const unsigned short* K0 = Kt + c0 * 64 * 64 + koff;
#pragma unroll
      for (int ct = 0; ct < 4; ++ct) {
        kf[ct][0] = *reinterpret_cast<const bfrag8*>(K0 + ct * 1024);
        kf[ct][1] = *reinterpret_cast<const bfrag8*>(K0 + ct * 1024 + 32);
      }
    }
    for (int kt = c0; kt < c1; ++kt) {
      int kv0 = kt * 64;
      // V loads (consumed by PV at bottom; wait hides behind QK+softmax)
      const unsigned short* Vtile = Vb + kv0 + voff;
      bfrag8 vf[2][4];
#pragma unroll
      for (int hh = 0; hh < 2; ++hh)
#pragma unroll
        for (int dt = 0; dt < 4; ++dt)
          vf[hh][dt] = *reinterpret_cast<const bfrag8*>(Vtile + dt * 16 * S_LEN + hh * 32);
      __builtin_amdgcn_sched_barrier(0);
      // swapped QK^T: lane (kb,fr) holds q-row (g*16+fr), k-cols ct*16+kb*4+j
      f32x4_t sc[2][4];
      __builtin_amdgcn_s_setprio(1);
#pragma unroll
      for (int ct = 0; ct < 4; ++ct) {
        f32x4_t z0 = (f32x4_t){0.f, 0.f, 0.f, 0.f};
        z0 = __builtin_amdgcn_mfma_f32_16x16x32_bf16(kf[ct][0], qf[0][0], z0, 0, 0, 0);
        sc[0][ct] = __builtin_amdgcn_mfma_f32_16x16x32_bf16(kf[ct][1], qf[0][1], z0, 0, 0, 0);
        f32x4_t z1 = (f32x4_t){0.f, 0.f, 0.f, 0.f};
        z1 = __builtin_amdgcn_mfma_f32_16x16x32_bf16(kf[ct][0], qf[1][0], z1, 0, 0, 0);
        sc[1][ct] = __builtin_amdgcn_mfma_f32_16x16x32_bf16(kf[ct][1], qf[1][1], z1, 0, 0, 0);
      }
      __builtin_amdgcn_s_setprio(0);
      // prefetch next tile's K now that QK consumed kf
      if (kt + 1 < c1) {
        const unsigned short* Kn = Kt + (kv0 + 64) * 64 + koff;
#pragma unroll
        for (int ct = 0; ct < 4; ++ct) {
          kf[ct][0] = *reinterpret_cast<const bfrag8*>(Kn + ct * 1024);
          kf[ct][1] = *reinterpret_cast<const bfrag8*>(Kn + ct * 1024 + 32);
        }
      }
      __builtin_amdgcn_sched_barrier(0);
      if (kt >= nf) {
#pragma unroll
        for (int g = 0; g < 2; ++g) {
          int grow = qrow0 + g * 16 + fr;
#pragma unroll
          for (int ct = 0; ct < 4; ++ct)
#pragma unroll
            for (int j = 0; j < 4; ++j)
              sc[g][ct][j] = ((kv0 + ct * 16 + kb * 4 + j) <= grow) ? sc[g][ct][j] : -1e30f;
        }
      }
      // row max: lane-local trees + 2 shuffles
      float pmax[2];
#pragma unroll
      for (int g = 0; g < 2; ++g) {
        float p0 = fmaxf(fmaxf(sc[g][0][0], sc[g][0][1]), fmaxf(sc[g][0][2], sc[g][0][3]));
        float p1 = fmaxf(fmaxf(sc[g][1][0], sc[g][1][1]), fmaxf(sc[g][1][2], sc[g][1][3]));
        float p2 = fmaxf(fmaxf(sc[g][2][0], sc[g][2][1]), fmaxf(sc[g][2][2], sc[g][2][3]));
        float p3 = fmaxf(fmaxf(sc[g][3][0], sc[g][3][1]), fmaxf(sc[g][3][2], sc[g][3][3]));
        float pm = fmaxf(fmaxf(p0, p1), fmaxf(p2, p3));
        pm = fmaxf(pm, __shfl_xor(pm, 16));
        pmax[g] = fmaxf(pm, __shfl_xor(pm, 32));
      }
      // defer-max: rescale only when a group's max rose by > 8 (exp2 domain)
      bool need = (pmax[0] > m_r[0] + 8.0f) || (pmax[1] > m_r[1] + 8.0f);
      if (__any(need)) {
#pragma unroll
        for (int g = 0; g < 2; ++g) {
          float mnew = fmaxf(m_r[g], pmax[g]);
          float a = exp2f(m_r[g] - mnew);
          l_r[g] *= a;
          m_r[g] = mnew;
#pragma unroll
          for (int j = 0; j < 4; ++j) {
            float aj = __shfl(a, rloc + j);
#pragma unroll
            for (int dt = 0; dt < 4; ++dt) acc[g][dt][j] *= aj;
          }
        }
      }
      // P = exp2(s - m); lane-local sums + 2 shuffles
#pragma unroll
      for (int g = 0; g < 2; ++g) {
        float s = 0.f;
#pragma unroll
        for (int ct = 0; ct < 4; ++ct)
#pragma unroll
          for (int j = 0; j < 4; ++j) {
            float p = exp2f(sc[g][ct][j] - m_r[g]);
            sc[g][ct][j] = p;
            s += p;
          }
        s += __shfl_xor(s, 16);
        s += __shfl_xor(s, 32);
        l_r[g] += s;
      }
      // P -> per-wave LDS, swizzled packed b64 writes (hw cvt_pk, proven innocent)
#pragma unroll
      for (int g = 0; g < 2; ++g)
#pragma unroll
        for (int ct = 0; ct < 4; ++ct) {
          unsigned int u01 = cvtpk_bf16(sc[g][ct][0], sc[g][ct][1]);
          unsigned int u23 = cvtpk_bf16(sc[g][ct][2], sc[g][ct][3]);
          unsigned long long w = ((unsigned long long)u23 << 32) | u01;
          *reinterpret_cast<unsigned long long*>(
              Pw + (g * 16 + fr) * 128 + ((ct * 32 + kb * 8) ^ swz)) = w;
        }
      // PV: A = P (rows = q), B = V
      __builtin_amdgcn_s_setprio(1);
#pragma unroll
      for (int hh = 0; hh < 2; ++hh) {
        bfrag8 pa0 = *reinterpret_cast<const bfrag8*>(Pw + fr * 128 + ((hh * 64 + kb * 16) ^ swz));
        bfrag8 pa1 = *reinterpret_cast<const bfrag8*>(Pw + (16 + fr) * 128 + ((hh * 64 + kb * 16) ^ swz));
#pragma unroll
        for (int dt = 0; dt < 4; ++dt) {
          acc[0][dt] = __builtin_amdgcn_mfma_f32_16x16x32_bf16(pa0, vf[hh][dt], acc[0][dt], 0, 0, 0);
          acc[1][dt] = __builtin_amdgcn_mfma_f32_16x16x32_bf16(pa1, vf[hh][dt], acc[1][dt], 0, 0, 0);
        }
      }
      __builtin_amdgcn_s_setprio(0);
    }
  }

  // ---- log-tree merge: (0<-1, 2<-3) then (0<-2). Regions reuse P LDS. ----
  float* stgA = (float*)SMEM;
  float* stgB = (float*)(SMEM + 9216);
  __syncthreads();
  if (wid == 1 || wid == 3) {
    float* R = (wid == 1) ? stgA : stgB;
#pragma unroll
    for (int g = 0; g < 2; ++g) {
#pragma unroll
      for (int dt = 0; dt < 4; ++dt)
#pragma unroll
        for (int j = 0; j < 4; ++j)
          R[(g * 16 + dt * 4 + j) * 64 + lane] = acc[g][dt][j];
      R[(32 + g * 2) * 64 + lane] = m_r[g];
      R[(33 + g * 2) * 64 + lane] = l_r[g];
    }
  }
  __syncthreads();
  if (wid == 0 || wid == 2) {
    float* R = (wid == 0) ? stgA : stgB;
#pragma unroll
    for (int g = 0; g < 2; ++g) {
      float mo = R[(32 + g * 2) * 64 + lane], lo = R[(33 + g * 2) * 64 + lane];
      float mm = fmaxf(m_r[g], mo);
      float ca = exp2f(m_r[g] - mm), cb = exp2f(mo - mm);
      l_r[g] = l_r[g] * ca + lo * cb;
      m_r[g] = mm;
#pragma unroll
      for (int j = 0; j < 4; ++j) {
        float caj = __shfl(ca, rloc + j);   // row-matched factors (R7 fix)
        float cbj = __shfl(cb, rloc + j);
#pragma unroll
        for (int dt = 0; dt < 4; ++dt)
          acc[g][dt][j] = acc[g][dt][j] * caj + R[(g * 16 + dt * 4 + j) * 64 + lane] * cbj;
      }
    }
    if (wid == 2) {
#pragma unroll
      for (int g = 0; g < 2; ++g) {
#pragma unroll
        for (int dt = 0; dt < 4; ++dt)
#pragma unroll
          for (int j = 0; j < 4; ++j)
            stgB[(g * 16 + dt * 4 + j) * 64 + lane] = acc[g][dt][j];
        stgB[(32 + g * 2) * 64 + lane] = m_r[g];
        stgB[(33 + g * 2) * 64 + lane] = l_r[g];
      }
    }
  }
  __syncthreads();
  if (wid == 0) {
#pragma unroll
    for (int g = 0; g < 2; ++g) {
      float mo = stgB[(32 + g * 2) * 64 + lane], lo = stgB[(33 + g * 2) * 64 + lane];
      float mm = fmaxf(m_r[g], mo);
      float ca = exp2f(m_r[g] - mm), cb = exp2f(mo - mm);
      l_r[g] = l_r[g] * ca + lo * cb;
#pragma unroll
      for (int j = 0; j < 4; ++j) {
        float caj = __shfl(ca, rloc + j);   // row-matched factors (R7 fix)
        float cbj = __shfl(cb, rloc + j);
#pragma unroll
        for (int dt = 0; dt < 4; ++dt)
          acc[g][dt][j] = acc[g][dt][j] * caj + stgB[(g * 16 + dt * 4 + j) * 64 + lane] * cbj;
      }
    }
    // normalize and write 32 rows x 64 cols
#pragma unroll
    for (int g = 0; g < 2; ++g)
#pragma unroll
      for (int j = 0; j < 4; ++j) {
        float lj = __shfl(l_r[g], rloc + j);
        float inv = 1.0f / lj;
        int grow = qrow0 + g * 16 + rloc + j;
#pragma unroll
        for (int dt = 0; dt < 4; ++dt)
          aout[(size_t)grow * (NH * HDIM) + head * 64 + dt * 16 + fr] = f2bf(acc[g][dt][j] * inv);
      }
  }
}

// ---------------- launch ----------------
extern "C" void kernel_launch(void* const* d_in, const int* in_sizes, int n_in,
                              void* d_out, int out_size, void* d_ws, size_t ws_size,
                              hipStream_t stream) {
  const float* x    = (const float*)d_in[0];
  const float* pcos = (const float*)d_in[1];
  const float* psin = (const float*)d_in[2];
  const float* wqkv = (const float*)d_in[3];
  const float* wo   = (const float*)d_in[4];
  float* out = (float*)d_out;

  char* ws = (char*)d_ws;
  unsigned short* xb    = (unsigned short*)ws;  ws += (size_t)S_LEN * DMODEL * 2;
  unsigned short* wqkvT = (unsigned short*)ws;  ws += (size_t)NQKV * DMODEL * 2;
  unsigned short* woT   = (unsigned short*)ws;  ws += (size_t)DMODEL * DMODEL * 2;
  float*          qkv   = (float*)ws;           ws += (size_t)S_LEN * NQKV * 4;
  unsigned short* Qh    = (unsigned short*)ws;  ws += (size_t)NH * S_LEN * HDIM * 2;
  unsigned short* Kh    = (unsigned short*)ws;  ws += (size_t)NKV * S_LEN * HDIM * 2;
  unsigned short* Vt    = (unsigned short*)ws;  ws += (size_t)NKV * HDIM * S_LEN * 2;
  unsigned short* aoutb = (unsigned short*)ws;  ws += (size_t)S_LEN * NH * HDIM * 2;

  convert_bf16<<<(S_LEN * DMODEL) / (256 * 4), 256, 0, stream>>>(x, xb, S_LEN * DMODEL);
  transpose_convert<<<dim3(NQKV / 32, DMODEL / 32, 1), dim3(32, 8), 0, stream>>>(
      wqkv, NQKV, 0, wqkvT, DMODEL, 0, DMODEL, NQKV);
  transpose_convert<<<dim3(DMODEL / 32, DMODEL / 32, 1), dim3(32, 8), 0, stream>>>(
      wo, DMODEL, 0, woT, DMODEL, 0, DMODEL, DMODEL);
  gemm_bf16<<<dim3(S_LEN / 128, NQKV / 128), 256, 0, stream>>>(xb, wqkvT, qkv, S_LEN, NQKV, DMODEL);
  rope_kernel<<<S_LEN, 256, 0, stream>>>(qkv, pcos, psin, Qh, Kh);
  transpose_convert<<<dim3(HDIM / 32, S_LEN / 32, NKV), dim3(32, 8), 0, stream>>>(
      qkv + 1280, NQKV, 64, Vt, S_LEN, (long)HDIM * S_LEN, S_LEN, HDIM);
  flash_attn<<<dim3(2048), 256, 0, stream>>>(Qh, Kh, Vt, aoutb);
  gemm_bf16<<<dim3(S_LEN / 128, DMODEL / 128), 256, 0, stream>>>(aoutb, woT, out, S_LEN, DMODEL, DMODEL);
}

// Round 11
// 204.068 us; speedup vs baseline: 2.2919x; 1.0074x over previous
//
#include <hip/hip_runtime.h>

#define S_LEN 4096
#define DMODEL 1024
#define NH 16
#define NKV 4
#define HDIM 64
#define NQKV 1536  /* (16+2*4)*64 */

typedef __attribute__((ext_vector_type(8))) short bfrag8;
typedef __attribute__((ext_vector_type(4))) float f32x4_t;

__device__ __forceinline__ unsigned short f2bf(float f) {
  unsigned int u = __builtin_bit_cast(unsigned int, f);
  return (unsigned short)((u + 0x7fffu + ((u >> 16) & 1u)) >> 16);
}

// packed f32x2 -> bf16x2, single HW instruction
__device__ __forceinline__ unsigned int cvtpk_bf16(float lo, float hi) {
  unsigned int r;
  asm("v_cvt_pk_bf16_f32 %0, %1, %2" : "=v"(r) : "v"(lo), "v"(hi));
  return r;
}

// bare v_exp_f32 (libm exp2f adds ~6-inst denormal fixup; our domain [-1e30, +8] is safe)
__device__ __forceinline__ float fexp2(float x) {
  float r;
  asm("v_exp_f32 %0, %1" : "=v"(r) : "v"(x));
  return r;
}

__device__ __forceinline__ float fmax3(float a, float b, float c) {
  float r;
  asm("v_max3_f32 %0, %1, %2, %3" : "=v"(r) : "v"(a), "v"(b), "v"(c));
  return r;
}

typedef __attribute__((address_space(3))) unsigned char lds_uc;
typedef const __attribute__((address_space(1))) unsigned char glob_uc;
__device__ __forceinline__ void gl16(const void* g, void* l) {
  __builtin_amdgcn_global_load_lds((glob_uc*)g, (lds_uc*)l, 16, 0, 0);
}

// ---------------- elementwise f32 -> bf16 ----------------
__global__ void convert_bf16(const float* __restrict__ in, unsigned short* __restrict__ out, int n) {
  int idx = (blockIdx.x * 256 + threadIdx.x) * 4;
  if (idx < n) {
    float4 v = *reinterpret_cast<const float4*>(in + idx);
    out[idx + 0] = f2bf(v.x);
    out[idx + 1] = f2bf(v.y);
    out[idx + 2] = f2bf(v.z);
    out[idx + 3] = f2bf(v.w);
  }
}

// ---------------- tiled transpose + convert: out[c][r] = bf16(in[r][c]) ----------------
__global__ void transpose_convert(const float* __restrict__ in, int ldin, long in_zstride,
                                  unsigned short* __restrict__ out, int ldout, long out_zstride,
                                  int R, int C) {
  __shared__ float tile[32][33];
  const float* inb = in + (size_t)blockIdx.z * in_zstride;
  unsigned short* outb = out + (size_t)blockIdx.z * out_zstride;
  int c0 = blockIdx.x * 32, r0 = blockIdx.y * 32;
  int tx = threadIdx.x, ty = threadIdx.y;  // 32 x 8
  for (int i = 0; i < 4; ++i) {
    int r = r0 + ty + i * 8;
    tile[ty + i * 8][tx] = inb[(size_t)r * ldin + c0 + tx];
  }
  __syncthreads();
  for (int i = 0; i < 4; ++i) {
    int c = c0 + ty + i * 8;
    outb[(size_t)c * ldout + r0 + tx] = f2bf(tile[tx][ty + i * 8]);
  }
}

// ---------------- RoPE; Q pre-scaled by 0.125*log2(e) so QK^T lands in exp2 domain ----------------
__global__ void rope_kernel(const float* __restrict__ qkv,
                            const float* __restrict__ pcos, const float* __restrict__ psin,
                            unsigned short* __restrict__ Qh, unsigned short* __restrict__ Kh) {
  const float SCL = 0.125f * 1.44269504f;
  int s = blockIdx.x;
  int t = threadIdx.x;
  const float* row = qkv + (size_t)s * NQKV;
  for (int p = t; p < 640; p += 256) {
    int i = p & 31;
    float c = pcos[s * 32 + i], sn = psin[s * 32 + i];
    if (p < 512) {
      int h = p >> 5;
      float te = row[h * 64 + 2 * i], to = row[h * 64 + 2 * i + 1];
      size_t base = ((size_t)h * S_LEN + s) * 64;
      Qh[base + 2 * i]     = f2bf((te * c - to * sn) * SCL);
      Qh[base + 2 * i + 1] = f2bf((te * sn + to * c) * SCL);
    } else {
      int hk = (p - 512) >> 5;
      float te = row[1024 + hk * 64 + 2 * i], to = row[1024 + hk * 64 + 2 * i + 1];
      size_t base = ((size_t)hk * S_LEN + s) * 64;
      Kh[base + 2 * i]     = f2bf(te * c - to * sn);
      Kh[base + 2 * i + 1] = f2bf(te * sn + to * c);
    }
  }
}

// ---------------- bf16 MFMA GEMM (m97 structure): C = A(MxK) * Bt(NxK)^T ----------------
__global__ __launch_bounds__(256) void gemm_bf16(
    const unsigned short* __restrict__ A,
    const unsigned short* __restrict__ Bt,
    float* __restrict__ C, int M, int N, int K) {
  __shared__ __align__(16) unsigned short As[128 * 32];
  __shared__ __align__(16) unsigned short Bs[128 * 32];
  int m0 = blockIdx.x * 128, n0 = blockIdx.y * 128;
  int t = threadIdx.x, lane = t & 63, wid = t >> 6;
  int wm = (wid >> 1) * 64, wn = (wid & 1) * 64;
  int fr = lane & 15, kb = lane >> 4;
  int srow = t >> 2, scol = (t & 3) * 8;
  const unsigned short* Ag0 = A + (size_t)(m0 + srow) * K + scol;
  const unsigned short* Ag1 = A + (size_t)(m0 + 64 + srow) * K + scol;
  const unsigned short* Bg0 = Bt + (size_t)(n0 + srow) * K + scol;
  const unsigned short* Bg1 = Bt + (size_t)(n0 + 64 + srow) * K + scol;
  char* AsW0 = (char*)As + wid * 1024;
  char* AsW1 = (char*)As + 4096 + wid * 1024;
  char* BsW0 = (char*)Bs + wid * 1024;
  char* BsW1 = (char*)Bs + 4096 + wid * 1024;

  f32x4_t acc[4][4];
#pragma unroll
  for (int r = 0; r < 4; ++r)
#pragma unroll
    for (int c = 0; c < 4; ++c) acc[r][c] = (f32x4_t){0.f, 0.f, 0.f, 0.f};

  for (int k0 = 0; k0 < K; k0 += 32) {
    __syncthreads();
    gl16(Ag0 + k0, AsW0);
    gl16(Ag1 + k0, AsW1);
    gl16(Bg0 + k0, BsW0);
    gl16(Bg1 + k0, BsW1);
    __syncthreads();
    bfrag8 af[4], bfr[4];
#pragma unroll
    for (int rb = 0; rb < 4; ++rb)
      af[rb] = *reinterpret_cast<const bfrag8*>(&As[(wm + rb * 16 + fr) * 32 + kb * 8]);
#pragma unroll
    for (int cb = 0; cb < 4; ++cb)
      bfr[cb] = *reinterpret_cast<const bfrag8*>(&Bs[(wn + cb * 16 + fr) * 32 + kb * 8]);
#pragma unroll
    for (int rb = 0; rb < 4; ++rb)
#pragma unroll
      for (int cb = 0; cb < 4; ++cb)
        acc[rb][cb] = __builtin_amdgcn_mfma_f32_16x16x32_bf16(af[rb], bfr[cb], acc[rb][cb], 0, 0, 0);
  }
  int rowg = (lane >> 4) * 4, colg = lane & 15;
#pragma unroll
  for (int rb = 0; rb < 4; ++rb)
#pragma unroll
    for (int cb = 0; cb < 4; ++cb)
#pragma unroll
      for (int j = 0; j < 4; ++j) {
        int r = m0 + wm + rb * 16 + rowg + j;
        int c = n0 + wn + cb * 16 + colg;
        C[(size_t)r * N + c] = acc[rb][cb][j];
      }
}

// ---------------- flash attention: causal, GQA, swapped-QK^T, 32 q-rows/wave, 4-way KV split ----------------
// Qh [NH][S][64] (pre-scaled), Kh [NKV][S][64], Vt [NKV][64][S], aout [S][NH*64] bf16
// MERGE NOTE: m_r/l_r live on lane fr (per q-row g*16+fr); acc[g][dt][j] holds q-row g*16+rloc+j.
// Any scale derived from m/l MUST be broadcast via __shfl(x, rloc+j) before touching acc. (R7 bug.)
__global__ __launch_bounds__(256) void flash_attn(
    const unsigned short* __restrict__ Qh,
    const unsigned short* __restrict__ Kh,
    const unsigned short* __restrict__ Vt,
    unsigned short* __restrict__ aout) {
  __shared__ __align__(16) char SMEM[18432];  // union: Pl[4][4KB] | 2 x merge region [36][64] f32
  int bid = blockIdx.x;
  int head = bid & 15, hk = head >> 2;
  int qt = 127 - (bid >> 4);  // longest chains dispatch first
  int qrow0 = qt * 32;
  int t = threadIdx.x, lane = t & 63, wid = t >> 6;
  int fr = lane & 15, kb = lane >> 4, rloc = kb * 4;
  char* Pw = SMEM + wid * 4096;
  int swz = (fr & 7) << 4;  // XOR swizzle within 128B P rows

  const unsigned short* Qbase = Qh + ((size_t)head * S_LEN + qrow0) * 64;
  bfrag8 qf[2][2];
  qf[0][0] = *reinterpret_cast<const bfrag8*>(Qbase + fr * 64 + kb * 8);
  qf[0][1] = *reinterpret_cast<const bfrag8*>(Qbase + fr * 64 + 32 + kb * 8);
  qf[1][0] = *reinterpret_cast<const bfrag8*>(Qbase + (16 + fr) * 64 + kb * 8);
  qf[1][1] = *reinterpret_cast<const bfrag8*>(Qbase + (16 + fr) * 64 + 32 + kb * 8);

  const unsigned short* Kt = Kh + (size_t)hk * S_LEN * 64;
  const unsigned short* Vb = Vt + (size_t)hk * 64 * S_LEN;
  int koff = fr * 64 + kb * 8;
  int voff = fr * S_LEN + kb * 8;

  float m_r[2] = {-1e30f, -1e30f}, l_r[2] = {0.f, 0.f};
  f32x4_t acc[2][4];
#pragma unroll
  for (int g = 0; g < 2; ++g)
#pragma unroll
    for (int dt = 0; dt < 4; ++dt) acc[g][dt] = (f32x4_t){0.f, 0.f, 0.f, 0.f};

  int ntt = (qrow0 + 95) / 64;
  int nf = (qrow0 >= 63) ? ((qrow0 - 63) / 64 + 1) : 0;
  int c0 = (wid * ntt) >> 2, c1 = ((wid + 1) * ntt) >> 2;

  if (c0 < c1) {
    bfrag8 kf[4][2];
    {
      const unsigned short* K0 = Kt + c0 * 64 * 64 + koff;
#pragma unroll
      for (int ct = 0; ct < 4; ++ct) {
        kf[ct][0] = *reinterpret_cast<const bfrag8*>(K0 + ct * 1024);
        kf[ct][1] = *reinterpret_cast<const bfrag8*>(K0 + ct * 1024 + 32);
      }
    }
    for (int kt = c0; kt < c1; ++kt) {
      int kv0 = kt * 64;
      const unsigned short* Vtile = Vb + kv0 + voff;
      bfrag8 vf[2][4];
#pragma unroll
      for (int hh = 0; hh < 2; ++hh)
#pragma unroll
        for (int dt = 0; dt < 4; ++dt)
          vf[hh][dt] = *reinterpret_cast<const bfrag8*>(Vtile + dt * 16 * S_LEN + hh * 32);
      __builtin_amdgcn_sched_barrier(0);
      // swapped QK^T
      f32x4_t sc[2][4];
      __builtin_amdgcn_s_setprio(1);
#pragma unroll
      for (int ct = 0; ct < 4; ++ct) {
        f32x4_t z0 = (f32x4_t){0.f, 0.f, 0.f, 0.f};
        z0 = __builtin_amdgcn_mfma_f32_16x16x32_bf16(kf[ct][0], qf[0][0], z0, 0, 0, 0);
        sc[0][ct] = __builtin_amdgcn_mfma_f32_16x16x32_bf16(kf[ct][1], qf[0][1], z0, 0, 0, 0);
        f32x4_t z1 = (f32x4_t){0.f, 0.f, 0.f, 0.f};
        z1 = __builtin_amdgcn_mfma_f32_16x16x32_bf16(kf[ct][0], qf[1][0], z1, 0, 0, 0);
        sc[1][ct] = __builtin_amdgcn_mfma_f32_16x16x32_bf16(kf[ct][1], qf[1][1], z1, 0, 0, 0);
      }
      __builtin_amdgcn_s_setprio(0);
      // prefetch next tile's K
      if (kt + 1 < c1) {
        const unsigned short* Kn = Kt + (kv0 + 64) * 64 + koff;
#pragma unroll
        for (int ct = 0; ct < 4; ++ct) {
          kf[ct][0] = *reinterpret_cast<const bfrag8*>(Kn + ct * 1024);
          kf[ct][1] = *reinterpret_cast<const bfrag8*>(Kn + ct * 1024 + 32);
        }
      }
      __builtin_amdgcn_sched_barrier(0);
      if (kt >= nf) {
#pragma unroll
        for (int g = 0; g < 2; ++g) {
          int grow = qrow0 + g * 16 + fr;
#pragma unroll
          for (int ct = 0; ct < 4; ++ct)
#pragma unroll
            for (int j = 0; j < 4; ++j)
              sc[g][ct][j] = ((kv0 + ct * 16 + kb * 4 + j) <= grow) ? sc[g][ct][j] : -1e30f;
        }
      }
      // row max: v_max3 chains + 2 shuffles
      float pmax[2];
#pragma unroll
      for (int g = 0; g < 2; ++g) {
        float pm = fmax3(sc[g][0][0], sc[g][0][1], sc[g][0][2]);
        pm = fmax3(pm, sc[g][0][3], sc[g][1][0]);
        pm = fmax3(pm, sc[g][1][1], sc[g][1][2]);
        pm = fmax3(pm, sc[g][1][3], sc[g][2][0]);
        pm = fmax3(pm, sc[g][2][1], sc[g][2][2]);
        pm = fmax3(pm, sc[g][2][3], sc[g][3][0]);
        pm = fmax3(pm, sc[g][3][1], sc[g][3][2]);
        pm = fmaxf(pm, sc[g][3][3]);
        pm = fmaxf(pm, __shfl_xor(pm, 16));
        pmax[g] = fmaxf(pm, __shfl_xor(pm, 32));
      }
      // defer-max: rescale only when a group's max rose by > 8 (exp2 domain)
      bool need = (pmax[0] > m_r[0] + 8.0f) || (pmax[1] > m_r[1] + 8.0f);
      if (__any(need)) {
#pragma unroll
        for (int g = 0; g < 2; ++g) {
          float mnew = fmaxf(m_r[g], pmax[g]);
          float a = fexp2(m_r[g] - mnew);
          l_r[g] *= a;
          m_r[g] = mnew;
#pragma unroll
          for (int j = 0; j < 4; ++j) {
            float aj = __shfl(a, rloc + j);
#pragma unroll
            for (int dt = 0; dt < 4; ++dt) acc[g][dt][j] *= aj;
          }
        }
      }
      // P = exp2(s - m) via bare v_exp_f32; lane-local sums + 2 shuffles
#pragma unroll
      for (int g = 0; g < 2; ++g) {
        float s = 0.f;
#pragma unroll
        for (int ct = 0; ct < 4; ++ct)
#pragma unroll
          for (int j = 0; j < 4; ++j) {
            float p = fexp2(sc[g][ct][j] - m_r[g]);
            sc[g][ct][j] = p;
            s += p;
          }
        s += __shfl_xor(s, 16);
        s += __shfl_xor(s, 32);
        l_r[g] += s;
      }
      // P -> per-wave LDS, swizzled packed b64 writes (hw cvt_pk)
#pragma unroll
      for (int g = 0; g < 2; ++g)
#pragma unroll
        for (int ct = 0; ct < 4; ++ct) {
          unsigned int u01 = cvtpk_bf16(sc[g][ct][0], sc[g][ct][1]);
          unsigned int u23 = cvtpk_bf16(sc[g][ct][2], sc[g][ct][3]);
          unsigned long long w = ((unsigned long long)u23 << 32) | u01;
          *reinterpret_cast<unsigned long long*>(
              Pw + (g * 16 + fr) * 128 + ((ct * 32 + kb * 8) ^ swz)) = w;
        }
      // PV
      __builtin_amdgcn_s_setprio(1);
#pragma unroll
      for (int hh = 0; hh < 2; ++hh) {
        bfrag8 pa0 = *reinterpret_cast<const bfrag8*>(Pw + fr * 128 + ((hh * 64 + kb * 16) ^ swz));
        bfrag8 pa1 = *reinterpret_cast<const bfrag8*>(Pw + (16 + fr) * 128 + ((hh * 64 + kb * 16) ^ swz));
#pragma unroll
        for (int dt = 0; dt < 4; ++dt) {
          acc[0][dt] = __builtin_amdgcn_mfma_f32_16x16x32_bf16(pa0, vf[hh][dt], acc[0][dt], 0, 0, 0);
          acc[1][dt] = __builtin_amdgcn_mfma_f32_16x16x32_bf16(pa1, vf[hh][dt], acc[1][dt], 0, 0, 0);
        }
      }
      __builtin_amdgcn_s_setprio(0);
    }
  }

  // ---- log-tree merge: (0<-1, 2<-3) then (0<-2). Regions reuse P LDS. ----
  float* stgA = (float*)SMEM;
  float* stgB = (float*)(SMEM + 9216);
  __syncthreads();
  if (wid == 1 || wid == 3) {
    float* R = (wid == 1) ? stgA : stgB;
#pragma unroll
    for (int g = 0; g < 2; ++g) {
#pragma unroll
      for (int dt = 0; dt < 4; ++dt)
#pragma unroll
        for (int j = 0; j < 4; ++j)
          R[(g * 16 + dt * 4 + j) * 64 + lane] = acc[g][dt][j];
      R[(32 + g * 2) * 64 + lane] = m_r[g];
      R[(33 + g * 2) * 64 + lane] = l_r[g];
    }
  }
  __syncthreads();
  if (wid == 0 || wid == 2) {
    float* R = (wid == 0) ? stgA : stgB;
#pragma unroll
    for (int g = 0; g < 2; ++g) {
      float mo = R[(32 + g * 2) * 64 + lane], lo = R[(33 + g * 2) * 64 + lane];
      float mm = fmaxf(m_r[g], mo);
      float ca = fexp2(m_r[g] - mm), cb = fexp2(mo - mm);
      l_r[g] = l_r[g] * ca + lo * cb;
      m_r[g] = mm;
#pragma unroll
      for (int j = 0; j < 4; ++j) {
        float caj = __shfl(ca, rloc + j);   // row-matched factors (R7 fix)
        float cbj = __shfl(cb, rloc + j);
#pragma unroll
        for (int dt = 0; dt < 4; ++dt)
          acc[g][dt][j] = acc[g][dt][j] * caj + R[(g * 16 + dt * 4 + j) * 64 + lane] * cbj;
      }
    }
    if (wid == 2) {
#pragma unroll
      for (int g = 0; g < 2; ++g) {
#pragma unroll
        for (int dt = 0; dt < 4; ++dt)
#pragma unroll
          for (int j = 0; j < 4; ++j)
            stgB[(g * 16 + dt * 4 + j) * 64 + lane] = acc[g][dt][j];
        stgB[(32 + g * 2) * 64 + lane] = m_r[g];
        stgB[(33 + g * 2) * 64 + lane] = l_r[g];
      }
    }
  }
  __syncthreads();
  if (wid == 0) {
#pragma unroll
    for (int g = 0; g < 2; ++g) {
      float mo = stgB[(32 + g * 2) * 64 + lane], lo = stgB[(33 + g * 2) * 64 + lane];
      float mm = fmaxf(m_r[g], mo);
      float ca = fexp2(m_r[g] - mm), cb = fexp2(mo - mm);
      l_r[g] = l_r[g] * ca + lo * cb;
#pragma unroll
      for (int j = 0; j < 4; ++j) {
        float caj = __shfl(ca, rloc + j);   // row-matched factors (R7 fix)
        float cbj = __shfl(cb, rloc + j);
#pragma unroll
        for (int dt = 0; dt < 4; ++dt)
          acc[g][dt][j] = acc[g][dt][j] * caj + stgB[(g * 16 + dt * 4 + j) * 64 + lane] * cbj;
      }
    }
    // normalize and write 32 rows x 64 cols
#pragma unroll
    for (int g = 0; g < 2; ++g)
#pragma unroll
      for (int j = 0; j < 4; ++j) {
        float lj = __shfl(l_r[g], rloc + j);
        float inv = 1.0f / lj;
        int grow = qrow0 + g * 16 + rloc + j;
#pragma unroll
        for (int dt = 0; dt < 4; ++dt)
          aout[(size_t)grow * (NH * HDIM) + head * 64 + dt * 16 + fr] = f2bf(acc[g][dt][j] * inv);
      }
  }
}

// ---------------- launch ----------------
extern "C" void kernel_launch(void* const* d_in, const int* in_sizes, int n_in,
                              void* d_out, int out_size, void* d_ws, size_t ws_size,
                              hipStream_t stream) {
  const float* x    = (const float*)d_in[0];
  const float* pcos = (const float*)d_in[1];
  const float* psin = (const float*)d_in[2];
  const float* wqkv = (const float*)d_in[3];
  const float* wo   = (const float*)d_in[4];
  float* out = (float*)d_out;

  char* ws = (char*)d_ws;
  unsigned short* xb    = (unsigned short*)ws;  ws += (size_t)S_LEN * DMODEL * 2;
  unsigned short* wqkvT = (unsigned short*)ws;  ws += (size_t)NQKV * DMODEL * 2;
  unsigned short* woT   = (unsigned short*)ws;  ws += (size_t)DMODEL * DMODEL * 2;
  float*          qkv   = (float*)ws;           ws += (size_t)S_LEN * NQKV * 4;
  unsigned short* Qh    = (unsigned short*)ws;  ws += (size_t)NH * S_LEN * HDIM * 2;
  unsigned short* Kh    = (unsigned short*)ws;  ws += (size_t)NKV * S_LEN * HDIM * 2;
  unsigned short* Vt    = (unsigned short*)ws;  ws += (size_t)NKV * HDIM * S_LEN * 2;
  unsigned short* aoutb = (unsigned short*)ws;  ws += (size_t)S_LEN * NH * HDIM * 2;

  convert_bf16<<<(S_LEN * DMODEL) / (256 * 4), 256, 0, stream>>>(x, xb, S_LEN * DMODEL);
  transpose_convert<<<dim3(NQKV / 32, DMODEL / 32, 1), dim3(32, 8), 0, stream>>>(
      wqkv, NQKV, 0, wqkvT, DMODEL, 0, DMODEL, NQKV);
  transpose_convert<<<dim3(DMODEL / 32, DMODEL / 32, 1), dim3(32, 8), 0, stream>>>(
      wo, DMODEL, 0, woT, DMODEL, 0, DMODEL, DMODEL);
  gemm_bf16<<<dim3(S_LEN / 128, NQKV / 128), 256, 0, stream>>>(xb, wqkvT, qkv, S_LEN, NQKV, DMODEL);
  rope_kernel<<<S_LEN, 256, 0, stream>>>(qkv, pcos, psin, Qh, Kh);
  transpose_convert<<<dim3(HDIM / 32, S_LEN / 32, NKV), dim3(32, 8), 0, stream>>>(
      qkv + 1280, NQKV, 64, Vt, S_LEN, (long)HDIM * S_LEN, S_LEN, HDIM);
  flash_attn<<<dim3(2048), 256, 0, stream>>>(Qh, Kh, Vt, aoutb);
  gemm_bf16<<<dim3(S_LEN / 128, DMODEL / 128), 256, 0, stream>>>(aoutb, woT, out, S_LEN, DMODEL, DMODEL);
}